// Round 11
// baseline (211.431 us; speedup 1.0000x reference)
//
#include <hip/hip_runtime.h>
#include <math.h>

#define NN 1024
#define FD 64
#define CH 32          // K*H
#define M1D 9
#define M2D 505
#define QH 253         // q in [0,252] stored
#define THALF 2273     // half-grid points
#define KPAD 4608
#define KSPLIT 24
#define KCHUNK 192     // 4608/24 = 6*32
#define G1SZ 291456    // 9*253*64*2
#define G1KS 8         // K-split factor for g1

#define FSQRT(x) __builtin_amdgcn_sqrtf(x)
#define FRCP(x)  __builtin_amdgcn_rcpf(x)

// ws layout (floats); ws_size = 256 MiB
#define OFF_WP    1024                    // 18 (pad 32)
#define OFF_SUMX  1056                    // 128 (pad to 1184)
#define OFF_G1    1184                    // 291456
#define OFF_GMAT  292640                  // 4608*64 = 294912
#define OFF_XL    587552                  // 65536
#define OFF_XR    653088                  // 65536
#define OFF_AGG   718624                  // 2048*512 = 1048576
#define OFF_PART  1767200                 // 24*131072 = 3145728
#define OFF_Y     4912928                 // 2048*4608 = 9437184 ; first 259072 ALIASED as T early
#define OFF_A2    14350112                // 16384*512 = 8388608
#define OFF_WT    22738720                // 64*512 = 32768
#define OFF_G1P   22771488                // 8*291456 = 2331648
#define OFF_ZG    25103136                // 2048*32 = 65536
// total = 25,168,672 floats = 100.7 MB

// builds T and Wt via inline __sincosf (round-10: prep_kernel folded in);
// block 0 also builds wp (9-pt twiddles) and zeros sumx.
__global__ __launch_bounds__(256) void build_tw_kernel(float* __restrict__ T,
                                                       float* __restrict__ Wt,
                                                       float* __restrict__ wp,
                                                       float* __restrict__ sumx) {
    int idx = blockIdx.x * 256 + threadIdx.x;
    if (blockIdx.x == 0) {
        if (threadIdx.x < M1D) {
            float ang = (float)threadIdx.x * (-6.2831853f / 9.0f);
            float s, c; __sincosf(ang, &s, &c);
            wp[2*threadIdx.x] = c; wp[2*threadIdx.x+1] = s;
        }
        if (threadIdx.x >= 64 && threadIdx.x < 192) sumx[threadIdx.x - 64] = 0.f;
    }
    if (idx < 506 * 512) {
        int r = idx >> 9, m2 = idx & 511;
        float v = 0.f;
        if (m2 < M2D) {
            int q = r >> 1;
            int t = (q * m2) % M2D;
            float ang = (float)t * (-6.2831853f / 505.0f);
            float s, c; __sincosf(ang, &s, &c);
            v = (r & 1) ? -s : c;
        }
        T[idx] = v;
    } else if (idx < 506 * 512 + 64 * 512) {
        int i2 = idx - 506 * 512;
        int m = i2 >> 9, col = i2 & 511;
        float v = 0.f;
        if (col < 506) {
            int q = col >> 1;
            int t = (q * m) % M2D;
            float ang = (float)t * (-6.2831853f / 505.0f);
            float s, c; __sincosf(ang, &s, &c);
            v = (col & 1) ? s : c;
        }
        Wt[i2] = v;
    }
}

// blocks 0..2047: proj (xl/xr); blocks 2048..2079: sumx partial column sums
__global__ __launch_bounds__(64) void proj_kernel(const float* __restrict__ x,
                                                  const float* __restrict__ Wl, const float* __restrict__ bl,
                                                  const float* __restrict__ Wr, const float* __restrict__ br,
                                                  float* __restrict__ xl, float* __restrict__ xr,
                                                  float* __restrict__ sumx) {
    int blk = blockIdx.x, tid = threadIdx.x;
    if (blk >= 2048) {
        int bb = blk - 2048;
        int b = bb >> 4, chunk = bb & 15;
        const float* xb = x + (size_t)b * NN * FD;
        float acc = 0.f;
        int j0 = chunk * 64;
        #pragma unroll 4
        for (int j = j0; j < j0 + 64; j++) acc += xb[j*FD + tid];
        atomicAdd(&sumx[b*FD + tid], acc);
        return;
    }
    int node = blk;
    __shared__ float xrow[FD];
    xrow[tid] = x[(size_t)node*FD + tid];
    __syncthreads();
    int c = tid & 31;
    const float* W = (tid < 32) ? Wl : Wr;
    float acc = (tid < 32) ? bl[c] : br[c];
    #pragma unroll
    for (int f = 0; f < FD; f++) acc += xrow[f] * W[f*CH + c];
    float* dst = (tid < 32) ? xl : xr;
    dst[(size_t)node*CH + c] = acc;
}

// 64 blocks (b*32+c): factored softmax denominators via sort + scans.
// Z[i] = exp(xr_i)*ss1[th] + exp(0.01*xr_i)*ps2[th], th = #{xl_j <= -xr_i}.
__global__ __launch_bounds__(256) void z_kernel(const float* __restrict__ xl,
                                                const float* __restrict__ xr,
                                                float* __restrict__ Zg) {
    int blk = blockIdx.x;
    int b = blk >> 5, c = blk & 31;
    int tid = threadIdx.x;
    __shared__ float v[1024];
    __shared__ float ss1[1025];
    __shared__ float ps2[1025];
    __shared__ float2 tsum[256];

    const float* xlb = xl + (((size_t)b << 10) * CH) + c;
    float lv[4];
    #pragma unroll
    for (int u = 0; u < 4; u++) lv[u] = xlb[(size_t)(tid + u*256) * CH];
    #pragma unroll
    for (int u = 0; u < 4; u++) v[tid + u*256] = lv[u];
    __syncthreads();

    // bitonic sort ascending (each pair handled once by its smaller index)
    for (int k = 2; k <= 1024; k <<= 1) {
        for (int j = k >> 1; j > 0; j >>= 1) {
            #pragma unroll
            for (int u = 0; u < 4; u++) {
                int i = tid + u*256;
                int ixj = i ^ j;
                if (ixj > i) {
                    float a = v[i], bb = v[ixj];
                    bool up = ((i & k) == 0);
                    if ((a > bb) == up) { v[i] = bb; v[ixj] = a; }
                }
            }
            __syncthreads();
        }
    }

    // per-thread 4 contiguous elements
    float e1[4], e2[4];
    #pragma unroll
    for (int u = 0; u < 4; u++) {
        float vv = v[4*tid + u];
        e1[u] = __expf(vv);
        e2[u] = __expf(0.01f * vv);
    }
    tsum[tid] = make_float2(e1[0]+e1[1]+e1[2]+e1[3], e2[0]+e2[1]+e2[2]+e2[3]);
    __syncthreads();
    // inclusive Hillis-Steele scan over 256 thread totals
    for (int d = 1; d < 256; d <<= 1) {
        float2 add = make_float2(0.f, 0.f);
        if (tid >= d) add = tsum[tid - d];
        __syncthreads();
        tsum[tid].x += add.x; tsum[tid].y += add.y;
        __syncthreads();
    }
    float tot1 = tsum[255].x;
    float2 off = (tid == 0) ? make_float2(0.f, 0.f) : tsum[tid-1];
    float p1 = off.x, p2 = off.y;
    #pragma unroll
    for (int u = 0; u < 4; u++) {
        int kk = 4*tid + u;
        ss1[kk] = tot1 - p1;      // suffix of e1 from kk (cancellation <=1e-5 rel, Z-dominant terms)
        ps2[kk] = p2;             // exclusive prefix of e2
        p1 += e1[u]; p2 += e2[u];
    }
    if (tid == 0) { ss1[1024] = 0.f; ps2[1024] = tsum[255].y; }
    __syncthreads();

    const float* xrb = xr + (((size_t)b << 10) * CH) + c;
    float* Zo = Zg + (((size_t)b << 10) * CH) + c;
    float xv[4];
    #pragma unroll
    for (int u = 0; u < 4; u++) xv[u] = xrb[(size_t)(tid + u*256) * CH];
    #pragma unroll
    for (int u = 0; u < 4; u++) {
        float tt = -xv[u];
        int lo = 0, hi = 1024;
        #pragma unroll
        for (int s = 0; s < 10; s++) {
            int mid = (lo + hi) >> 1;
            if (v[mid] > tt) hi = mid; else lo = mid + 1;
        }
        float Z = __expf(xv[u]) * ss1[lo] + __expf(0.01f * xv[u]) * ps2[lo];
        Zo[(size_t)(tid + u*256) * CH] = FRCP(Z);
    }
}

// G1 partials: grid (8 mtiles, 9 m1, 8 ksplit), one-shot K=64 tile GEMM
__global__ __launch_bounds__(256) void g1_gemm_kernel(const float* __restrict__ T,
                                                      const float* __restrict__ Wm,
                                                      float* __restrict__ G1p) {
    int mt = blockIdx.x, m1 = blockIdx.y, ks = blockIdx.z;
    int tid = threadIdx.x;
    __shared__ float As[64][68];
    __shared__ float Bs[64][64];
    int r0 = mt * 64, k0 = ks * 64;
    const float* Wmb = Wm + (size_t)m1 * M2D * FD;
    float ra[16], rb[16];
    #pragma unroll
    for (int i = 0; i < 16; i++) {
        int l = tid + i*256;
        int r = l >> 6, k = l & 63;
        int rr = r0 + r;
        ra[i] = (rr < 506) ? T[(size_t)rr*512 + k0 + k] : 0.f;
    }
    #pragma unroll
    for (int i = 0; i < 16; i++) {
        int l = tid + i*256;
        int k = l >> 6, f = l & 63;
        int krow = k0 + k;
        rb[i] = (krow < M2D) ? Wmb[(size_t)krow*FD + f] : 0.f;
    }
    #pragma unroll
    for (int i = 0; i < 16; i++) {
        int l = tid + i*256;
        As[l & 63][l >> 6] = ra[i];
    }
    #pragma unroll
    for (int i = 0; i < 16; i++) {
        int l = tid + i*256;
        Bs[l >> 6][l & 63] = rb[i];
    }
    __syncthreads();
    float acc[4][4] = {{0.f}};
    int tm = (tid >> 4) * 4, tf = (tid & 15) * 4;
    #pragma unroll 8
    for (int k = 0; k < 64; k++) {
        float4 a = *(const float4*)&As[k][tm];
        float4 b = *(const float4*)&Bs[k][tf];
        acc[0][0] += a.x*b.x; acc[0][1] += a.x*b.y; acc[0][2] += a.x*b.z; acc[0][3] += a.x*b.w;
        acc[1][0] += a.y*b.x; acc[1][1] += a.y*b.y; acc[1][2] += a.y*b.z; acc[1][3] += a.y*b.w;
        acc[2][0] += a.z*b.x; acc[2][1] += a.z*b.y; acc[2][2] += a.z*b.z; acc[2][3] += a.z*b.w;
        acc[3][0] += a.w*b.x; acc[3][1] += a.w*b.y; acc[3][2] += a.w*b.z; acc[3][3] += a.w*b.w;
    }
    float* G1k = G1p + (size_t)ks * G1SZ;
    #pragma unroll
    for (int i = 0; i < 4; i++) {
        int r = r0 + tm + i;
        if (r >= 506) continue;
        int q = r >> 1, reim = r & 1;
        size_t base = (size_t)(m1*QH + q) * 128;
        #pragma unroll
        for (int j = 0; j < 4; j++)
            G1k[base + (tf + j)*2 + reim] = acc[i][j];
    }
}

// fold the 8 K-split partials
__global__ __launch_bounds__(256) void g1_reduce_kernel(const float* __restrict__ G1p,
                                                        float* __restrict__ G1) {
    int idx = blockIdx.x * 256 + threadIdx.x;
    if (idx >= G1SZ/4) return;
    const float4* p = (const float4*)G1p;
    float4 s = p[idx];
    #pragma unroll
    for (int ks = 1; ks < G1KS; ks++) {
        float4 v = p[(size_t)ks*(G1SZ/4) + idx];
        s.x += v.x; s.y += v.y; s.z += v.z; s.w += v.w;
    }
    ((float4*)G1)[idx] = s;
}

// Gmat[2t..2t+1][f] from G1: fold 9-point DFT over m1, Hermitian weight, 1/4545
__global__ __launch_bounds__(64) void gmat_kernel(const float* __restrict__ G1,
                                                  const float* __restrict__ wp,
                                                  float* __restrict__ Gmat) {
    int t = blockIdx.x;
    int f = threadIdx.x;
    if (t >= THALF) {
        Gmat[(size_t)(2*t)*FD + f] = 0.f;
        Gmat[(size_t)(2*t+1)*FD + f] = 0.f;
        return;
    }
    int p, q;
    if (t < QH) { p = 0; q = t; }
    else { int u = t - QH; p = 1 + u / M2D; q = u % M2D; }
    float gr = 0.f, gi = 0.f;
    #pragma unroll
    for (int m1 = 0; m1 < M1D; m1++) {
        float ar, ai;
        if (q < QH) { size_t o = ((size_t)(m1*QH + q)*FD + f)*2; ar = G1[o]; ai = G1[o+1]; }
        else        { size_t o = ((size_t)(m1*QH + (M2D - q))*FD + f)*2; ar = G1[o]; ai = -G1[o+1]; }
        int pm = (p * m1) % M1D;
        float cr = wp[2*pm], ci = -wp[2*pm+1];
        gr += ar*cr - ai*ci;
        gi += ar*ci + ai*cr;
    }
    float scale = (t == 0) ? (1.0f/4545.0f) : (2.0f/4545.0f);
    Gmat[(size_t)(2*t)*FD + f]   =  gr * scale;
    Gmat[(size_t)(2*t+1)*FD + f] = -gi * scale;
}

// one block (256 thr) per node. Round-10: Z-pass removed (Zg precomputed by
// z_kernel); only active-list scan + sparse clamped gather remain.
__global__ __launch_bounds__(256) void attn_agg_kernel(const float* __restrict__ x,
                                                       const float* __restrict__ adj,
                                                       const float* __restrict__ xl,
                                                       const float* __restrict__ xr,
                                                       const float* __restrict__ Zg,
                                                       const float* __restrict__ sumx,
                                                       float* __restrict__ agg) {
    int node = blockIdx.x;
    int b = node >> 10;
    int tid = threadIdx.x;
    __shared__ float xr_s[CH], Zinv[CH], Sinv[CH];
    __shared__ float red[8][CH];
    __shared__ int act_list[NN + 8];
    __shared__ int act_n;
    __shared__ float qv2[64][CH];

    if (tid < CH) {
        xr_s[tid] = xr[(size_t)node*CH + tid];
        Zinv[tid] = Zg[(size_t)node*CH + tid];
    }
    if (tid == 0) act_n = 0;
    const float* adjrow = adj + (size_t)node * NN;
    float av[4];
    #pragma unroll
    for (int u = 0; u < 4; u++) av[u] = adjrow[tid + u*256];
    __syncthreads();
    #pragma unroll
    for (int u = 0; u < 4; u++)
        if (av[u] != 0.f) { int p = atomicAdd(&act_n, 1); act_list[p] = tid + u*256; }
    __syncthreads();
    int nact = act_n;

    int c = tid & 31, jl = tid >> 5;
    const float* xlb = xl + ((size_t)b << 10) * CH;
    int f = tid & 63, n0 = tid >> 6;
    int g = f >> 4;
    int c0 = n0*4 + g, c1 = (n0+4)*4 + g;
    const float* xb = x + ((size_t)b << 10) * FD;
    float acc0 = 0.f, acc1 = 0.f, sacc = 0.f;

    for (int base = 0; base < nact; base += 64) {
        int cnt = min(64, nact - base);
        int cntp = (cnt + 7) & ~7;
        for (int u = tid; u < (cnt << 5); u += 256) {
            int jj = u >> 5, cc = u & 31;
            int j = act_list[base + jj];
            float s = xlb[j*CH + cc] + xr_s[cc];
            s = s > 0.f ? s : 0.01f * s;
            float pv = __expf(s) * Zinv[cc];
            float qq = fmaxf(pv, 1e-6f) - 1e-6f;
            qv2[jj][cc] = qq;
            sacc += qq;
        }
        for (int u = tid + (cnt << 5); u < (cntp << 5); u += 256)
            qv2[u >> 5][u & 31] = 0.f;
        if (tid < cntp - cnt) act_list[base + cnt + tid] = act_list[base];
        __syncthreads();
        for (int jb = 0; jb < cntp; jb += 8) {
            float xv[8];
            #pragma unroll
            for (int u = 0; u < 8; u++) xv[u] = xb[act_list[base + jb + u]*FD + f];
            #pragma unroll
            for (int u = 0; u < 8; u++) {
                acc0 += qv2[jb+u][c0] * xv[u];
                acc1 += qv2[jb+u][c1] * xv[u];
            }
        }
        __syncthreads();
    }
    red[jl][c] = sacc;
    __syncthreads();
    if (tid < CH) {
        float s = 0.f;
        #pragma unroll
        for (int r = 0; r < 8; r++) s += red[r][tid];
        Sinv[tid] = FRCP(s + (float)NN * 1e-6f);
    }
    __syncthreads();
    float sx = sumx[b*FD + f] * 1e-6f;
    agg[(size_t)node*512 + n0*FD + f]       = (acc0 + sx) * Sinv[c0];
    agg[(size_t)node*512 + (n0+4)*FD + f]   = (acc1 + sx) * Sinv[c1];
}

// A2 = agg @ Wt : [16384 x 64] @ [64 x 512]. grid (256 mtiles, 8 ntiles)
__global__ __launch_bounds__(256) void a_gemm_kernel(const float* __restrict__ agg,
                                                     const float* __restrict__ Wt,
                                                     float* __restrict__ A2) {
    int mt = blockIdx.x, nt = blockIdx.y;
    int tid = threadIdx.x;
    __shared__ float As2[64][68];
    __shared__ float Bs[64][64];
    float acc[4][4] = {{0.f}};
    int tm = (tid >> 4) * 4, tf = (tid & 15) * 4;
    float ra[16], rb[16];
    #pragma unroll
    for (int i = 0; i < 16; i++) {
        int l = tid + i*256;
        int r = l >> 6, k = l & 63;
        ra[i] = agg[(size_t)(mt*64 + r)*64 + k];
    }
    #pragma unroll
    for (int i = 0; i < 16; i++) {
        int l = tid + i*256;
        int k = l >> 6, cc = l & 63;
        rb[i] = Wt[(size_t)k*512 + nt*64 + cc];
    }
    #pragma unroll
    for (int i = 0; i < 16; i++) {
        int l = tid + i*256;
        As2[l & 63][l >> 6] = ra[i];
    }
    #pragma unroll
    for (int i = 0; i < 16; i++) {
        int l = tid + i*256;
        Bs[l >> 6][l & 63] = rb[i];
    }
    __syncthreads();
    #pragma unroll 8
    for (int k = 0; k < 64; k++) {
        float4 a = *(const float4*)&As2[k][tm];
        float4 b = *(const float4*)&Bs[k][tf];
        acc[0][0] += a.x*b.x; acc[0][1] += a.x*b.y; acc[0][2] += a.x*b.z; acc[0][3] += a.x*b.w;
        acc[1][0] += a.y*b.x; acc[1][1] += a.y*b.y; acc[1][2] += a.y*b.z; acc[1][3] += a.y*b.w;
        acc[2][0] += a.z*b.x; acc[2][1] += a.z*b.y; acc[2][2] += a.z*b.z; acc[2][3] += a.z*b.w;
        acc[3][0] += a.w*b.x; acc[3][1] += a.w*b.y; acc[3][2] += a.w*b.z; acc[3][3] += a.w*b.w;
    }
    #pragma unroll
    for (int i = 0; i < 4; i++) {
        float4 v = make_float4(acc[i][0], acc[i][1], acc[i][2], acc[i][3]);
        *(float4*)&A2[(size_t)(mt*64 + tm + i)*512 + nt*64 + tf] = v;
    }
}

// one block (256 thr) per node: Y half-grid from A2.
__global__ __launch_bounds__(256) void y_kernel(const float* __restrict__ A2,
                                                float* __restrict__ Y) {
    int node = blockIdx.x;
    int tid = threadIdx.x;
    __shared__ float2 AL[8][QH];

    const float2* A2c = (const float2*)(A2 + (size_t)(node*8)*512);
    float2 rl[8];
    #pragma unroll
    for (int i = 0; i < 8; i++) {
        int idx = tid + i*256;
        rl[i] = (idx < 8*QH) ? A2c[(idx/QH)*256 + (idx%QH)] : make_float2(0.f, 0.f);
    }
    #pragma unroll
    for (int i = 0; i < 8; i++) {
        int idx = tid + i*256;
        if (idx < 8*QH) AL[idx/QH][idx%QH] = rl[i];
    }
    __syncthreads();

    float* Yrow = Y + (size_t)node * KPAD;
    if (tid < KPAD - 2*THALF) Yrow[2*THALF + tid] = 0.f;

    const float CPt[5] = {1.0f, 0.766044443119f, 0.173648177667f, -0.5f, -0.939692620786f};
    const float SPt[5] = {0.0f, -0.642787609687f, -0.984807753012f, -0.866025403784f, -0.342020143326f};

    #define Y_BODY(P, Q, QQ, CSIGN)                                            \
    {                                                                          \
        float cp = CPt[P], sp = SPt[P];                                        \
        float Pr = 1.f, Pi = 0.f, rp2 = 1.f;                                   \
        _Pragma("unroll")                                                      \
        for (int n = 0; n < 8; n++) {                                          \
            float2 Av = AL[n][QQ];                                             \
            float Ar = Av.x, Ai = (CSIGN) * Av.y;                              \
            float Xr = cp - Ar, Xi = sp - Ai;                                  \
            rp2 *= (Xr*Xr + Xi*Xi);                                            \
            float nPr = Pr*Xr - Pi*Xi;                                         \
            Pi = Pr*Xi + Pi*Xr; Pr = nPr;                                      \
        }                                                                      \
        float pAbs = FSQRT(Pr*Pr + Pi*Pi);                                     \
        float rp8 = FSQRT(FSQRT(FSQRT(FSQRT(rp2))));                           \
        float s = rp8 * FRCP(fmaxf(pAbs, 1e-20f));                             \
        int t = (P == 0) ? (Q) : (QH + ((P)-1)*M2D + (Q));                     \
        *(float2*)&Yrow[2*t] = make_float2(s*Pr, s*Pi);                        \
    }

    if (tid < QH) Y_BODY(0, tid, tid, 1.f);
    #pragma unroll
    for (int p = 1; p <= 4; p++) {
        {
            int q = tid;
            int qq = (q < QH) ? q : (M2D - q);
            float cs = (q < QH) ? 1.f : -1.f;
            Y_BODY(p, q, qq, cs);
        }
        {
            int q = tid + 256;
            if (q < M2D) {
                int qq = M2D - q;
                Y_BODY(p, q, qq, -1.f);
            }
        }
    }
    #undef Y_BODY
}

// partials[kc] = Y[:, kc-chunk] @ Gmat[kc-chunk, :] ; grid (32 Mtiles, 24 kc)
__global__ __launch_bounds__(256) void gemm_kernel(const float* __restrict__ Y,
                                                   const float* __restrict__ Gmat,
                                                   float* __restrict__ part) {
    int mtile = blockIdx.x, kc = blockIdx.y;
    int tid = threadIdx.x;
    __shared__ float Yt2[32][68];
    __shared__ float Gt[32][64];
    int m0 = mtile * 64;
    int k0 = kc * KCHUNK;
    float acc[4][4] = {{0.f}};
    int tm = (tid >> 4) * 4;
    int tf = (tid & 15) * 4;
    float ra[8], rb[8];
    #pragma unroll
    for (int i = 0; i < 8; i++) {
        int l = tid + i*256;
        int r = l >> 5, kk = l & 31;
        ra[i] = Y[(size_t)(m0 + r)*KPAD + k0 + kk];
    }
    #pragma unroll
    for (int i = 0; i < 8; i++) {
        int l = tid + i*256;
        int kk = l >> 6, cc = l & 63;
        rb[i] = Gmat[(size_t)(k0 + kk)*FD + cc];
    }
    for (int ks = 0; ks < KCHUNK; ks += 32) {
        #pragma unroll
        for (int i = 0; i < 8; i++) {
            int l = tid + i*256;
            Yt2[l & 31][l >> 5] = ra[i];
        }
        #pragma unroll
        for (int i = 0; i < 8; i++) {
            int l = tid + i*256;
            Gt[l >> 6][l & 63] = rb[i];
        }
        __syncthreads();
        if (ks + 32 < KCHUNK) {
            int kn = k0 + ks + 32;
            #pragma unroll
            for (int i = 0; i < 8; i++) {
                int l = tid + i*256;
                int r = l >> 5, kk = l & 31;
                ra[i] = Y[(size_t)(m0 + r)*KPAD + kn + kk];
            }
            #pragma unroll
            for (int i = 0; i < 8; i++) {
                int l = tid + i*256;
                int kk = l >> 6, cc = l & 63;
                rb[i] = Gmat[(size_t)(kn + kk)*FD + cc];
            }
        }
        #pragma unroll 8
        for (int k = 0; k < 32; k++) {
            float4 a = *(const float4*)&Yt2[k][tm];
            float4 b = *(const float4*)&Gt[k][tf];
            acc[0][0] += a.x*b.x; acc[0][1] += a.x*b.y; acc[0][2] += a.x*b.z; acc[0][3] += a.x*b.w;
            acc[1][0] += a.y*b.x; acc[1][1] += a.y*b.y; acc[1][2] += a.y*b.z; acc[1][3] += a.y*b.w;
            acc[2][0] += a.z*b.x; acc[2][1] += a.z*b.y; acc[2][2] += a.z*b.z; acc[2][3] += a.z*b.w;
            acc[3][0] += a.w*b.x; acc[3][1] += a.w*b.y; acc[3][2] += a.w*b.z; acc[3][3] += a.w*b.w;
        }
        __syncthreads();
    }
    float* prow = part + (size_t)kc * (2048*FD);
    #pragma unroll
    for (int i = 0; i < 4; i++) {
        float4 v = make_float4(acc[i][0], acc[i][1], acc[i][2], acc[i][3]);
        *(float4*)&prow[(size_t)(m0 + tm + i)*FD + tf] = v;
    }
}

// sum 24 partials + bias + mask -> out
__global__ __launch_bounds__(256) void reduce_kernel(const float* __restrict__ part,
                                                     const float* __restrict__ bm,
                                                     const float* __restrict__ mask,
                                                     float* __restrict__ out) {
    int idx = blockIdx.x * 256 + threadIdx.x;
    if (idx >= 32768) return;
    const float4* p4 = (const float4*)part;
    float4 s = p4[idx];
    #pragma unroll
    for (int kc = 1; kc < KSPLIT; kc++) {
        float4 v = p4[(size_t)kc*32768 + idx];
        s.x += v.x; s.y += v.y; s.z += v.z; s.w += v.w;
    }
    int f0 = (idx & 15) * 4;
    int node = idx >> 4;
    float mk = mask[node];
    s.x = (s.x + bm[f0])   * mk;
    s.y = (s.y + bm[f0+1]) * mk;
    s.z = (s.z + bm[f0+2]) * mk;
    s.w = (s.w + bm[f0+3]) * mk;
    ((float4*)out)[idx] = s;
}

extern "C" void kernel_launch(void* const* d_in, const int* in_sizes, int n_in,
                              void* d_out, int out_size, void* d_ws, size_t ws_size,
                              hipStream_t stream) {
    const float* x    = (const float*)d_in[0];
    const float* adj  = (const float*)d_in[1];
    const float* mask = (const float*)d_in[2];
    const float* Wl   = (const float*)d_in[3];
    const float* bl   = (const float*)d_in[4];
    const float* Wr   = (const float*)d_in[5];
    const float* br   = (const float*)d_in[6];
    const float* Wm   = (const float*)d_in[9];
    const float* bm   = (const float*)d_in[10];
    float* out = (float*)d_out;
    float* ws  = (float*)d_ws;

    float* wp   = ws + OFF_WP;
    float* sumx = ws + OFF_SUMX;
    float* G1   = ws + OFF_G1;
    float* Gmat = ws + OFF_GMAT;
    float* xl   = ws + OFF_XL;
    float* xr   = ws + OFF_XR;
    float* agg  = ws + OFF_AGG;
    float* part = ws + OFF_PART;
    float* T    = ws + OFF_Y;     // alias: T dead before y_kernel writes Y
    float* Y    = ws + OFF_Y;
    float* A2   = ws + OFF_A2;
    float* Wt   = ws + OFF_WT;
    float* G1p  = ws + OFF_G1P;
    float* Zg   = ws + OFF_ZG;

    hipLaunchKernelGGL(build_tw_kernel, dim3((506*512 + 64*512 + 255)/256), dim3(256), 0, stream, T, Wt, wp, sumx);
    hipLaunchKernelGGL(proj_kernel, dim3(2080), dim3(64), 0, stream, x, Wl, bl, Wr, br, xl, xr, sumx);
    hipLaunchKernelGGL(z_kernel, dim3(64), dim3(256), 0, stream, xl, xr, Zg);
    hipLaunchKernelGGL(g1_gemm_kernel, dim3(8, 9, G1KS), dim3(256), 0, stream, T, Wm, G1p);
    hipLaunchKernelGGL(g1_reduce_kernel, dim3((G1SZ/4 + 255)/256), dim3(256), 0, stream, G1p, G1);
    hipLaunchKernelGGL(gmat_kernel, dim3(KPAD/2), dim3(64), 0, stream, G1, wp, Gmat);
    hipLaunchKernelGGL(attn_agg_kernel, dim3(2048), dim3(256), 0, stream, x, adj, xl, xr, Zg, sumx, agg);
    hipLaunchKernelGGL(a_gemm_kernel, dim3(256, 8), dim3(256), 0, stream, agg, Wt, A2);
    hipLaunchKernelGGL(y_kernel, dim3(2048), dim3(256), 0, stream, A2, Y);
    hipLaunchKernelGGL(gemm_kernel, dim3(32, KSPLIT), dim3(256), 0, stream, Y, Gmat, part);
    hipLaunchKernelGGL(reduce_kernel, dim3(128), dim3(256), 0, stream, part, bm, mask, out);
}

// Round 12
// 205.720 us; speedup vs baseline: 1.0278x; 1.0278x over previous
//
#include <hip/hip_runtime.h>
#include <math.h>

#define NN 1024
#define FD 64
#define CH 32          // K*H
#define M1D 9
#define M2D 505
#define QH 253         // q in [0,252] stored
#define THALF 2273     // half-grid points
#define KPAD 4608
#define KSPLIT 24
#define KCHUNK 192     // 4608/24 = 6*32
#define G1SZ 291456    // 9*253*64*2
#define G1KS 8         // K-split factor for g1

#define FSQRT(x) __builtin_amdgcn_sqrtf(x)
#define FRCP(x)  __builtin_amdgcn_rcpf(x)

// ws layout (floats); ws_size = 256 MiB
#define OFF_WP    1024                    // 18 (pad 32)
#define OFF_SUMX  1056                    // 128 (pad to 1184)
#define OFF_G1    1184                    // 291456
#define OFF_GMAT  292640                  // 4608*64 = 294912
#define OFF_XL    587552                  // 65536
#define OFF_XR    653088                  // 65536
#define OFF_AGG   718624                  // 2048*512 = 1048576
#define OFF_PART  1767200                 // 24*131072 = 3145728
#define OFF_Y     4912928                 // 2048*4608 = 9437184 ; first 259072 ALIASED as T early
#define OFF_A2    14350112                // 16384*512 = 8388608
#define OFF_WT    22738720                // 64*512 = 32768
#define OFF_G1P   22771488                // 8*291456 = 2331648
// total = 25,103,136 floats = 100.4 MB

// builds T and Wt via inline __sincosf; block 0 also builds wp and zeros sumx.
__global__ __launch_bounds__(256) void build_tw_kernel(float* __restrict__ T,
                                                       float* __restrict__ Wt,
                                                       float* __restrict__ wp,
                                                       float* __restrict__ sumx) {
    int idx = blockIdx.x * 256 + threadIdx.x;
    if (blockIdx.x == 0) {
        if (threadIdx.x < M1D) {
            float ang = (float)threadIdx.x * (-6.2831853f / 9.0f);
            float s, c; __sincosf(ang, &s, &c);
            wp[2*threadIdx.x] = c; wp[2*threadIdx.x+1] = s;
        }
        if (threadIdx.x >= 64 && threadIdx.x < 192) sumx[threadIdx.x - 64] = 0.f;
    }
    if (idx < 506 * 512) {
        int r = idx >> 9, m2 = idx & 511;
        float v = 0.f;
        if (m2 < M2D) {
            int q = r >> 1;
            int t = (q * m2) % M2D;
            float ang = (float)t * (-6.2831853f / 505.0f);
            float s, c; __sincosf(ang, &s, &c);
            v = (r & 1) ? -s : c;
        }
        T[idx] = v;
    } else if (idx < 506 * 512 + 64 * 512) {
        int i2 = idx - 506 * 512;
        int m = i2 >> 9, col = i2 & 511;
        float v = 0.f;
        if (col < 506) {
            int q = col >> 1;
            int t = (q * m) % M2D;
            float ang = (float)t * (-6.2831853f / 505.0f);
            float s, c; __sincosf(ang, &s, &c);
            v = (col & 1) ? s : c;
        }
        Wt[i2] = v;
    }
}

// blocks 0..2047: proj (xl/xr); blocks 2048..2079: sumx partial column sums
__global__ __launch_bounds__(64) void proj_kernel(const float* __restrict__ x,
                                                  const float* __restrict__ Wl, const float* __restrict__ bl,
                                                  const float* __restrict__ Wr, const float* __restrict__ br,
                                                  float* __restrict__ xl, float* __restrict__ xr,
                                                  float* __restrict__ sumx) {
    int blk = blockIdx.x, tid = threadIdx.x;
    if (blk >= 2048) {
        int bb = blk - 2048;
        int b = bb >> 4, chunk = bb & 15;
        const float* xb = x + (size_t)b * NN * FD;
        float acc = 0.f;
        int j0 = chunk * 64;
        #pragma unroll 4
        for (int j = j0; j < j0 + 64; j++) acc += xb[j*FD + tid];
        atomicAdd(&sumx[b*FD + tid], acc);
        return;
    }
    int node = blk;
    __shared__ float xrow[FD];
    xrow[tid] = x[(size_t)node*FD + tid];
    __syncthreads();
    int c = tid & 31;
    const float* W = (tid < 32) ? Wl : Wr;
    float acc = (tid < 32) ? bl[c] : br[c];
    #pragma unroll
    for (int f = 0; f < FD; f++) acc += xrow[f] * W[f*CH + c];
    float* dst = (tid < 32) ? xl : xr;
    dst[(size_t)node*CH + c] = acc;
}

// G1 partials: grid (8 mtiles, 9 m1, 8 ksplit), one-shot K=64 tile GEMM
__global__ __launch_bounds__(256) void g1_gemm_kernel(const float* __restrict__ T,
                                                      const float* __restrict__ Wm,
                                                      float* __restrict__ G1p) {
    int mt = blockIdx.x, m1 = blockIdx.y, ks = blockIdx.z;
    int tid = threadIdx.x;
    __shared__ float As[64][68];
    __shared__ float Bs[64][64];
    int r0 = mt * 64, k0 = ks * 64;
    const float* Wmb = Wm + (size_t)m1 * M2D * FD;
    float ra[16], rb[16];
    #pragma unroll
    for (int i = 0; i < 16; i++) {
        int l = tid + i*256;
        int r = l >> 6, k = l & 63;
        int rr = r0 + r;
        ra[i] = (rr < 506) ? T[(size_t)rr*512 + k0 + k] : 0.f;
    }
    #pragma unroll
    for (int i = 0; i < 16; i++) {
        int l = tid + i*256;
        int k = l >> 6, f = l & 63;
        int krow = k0 + k;
        rb[i] = (krow < M2D) ? Wmb[(size_t)krow*FD + f] : 0.f;
    }
    #pragma unroll
    for (int i = 0; i < 16; i++) {
        int l = tid + i*256;
        As[l & 63][l >> 6] = ra[i];
    }
    #pragma unroll
    for (int i = 0; i < 16; i++) {
        int l = tid + i*256;
        Bs[l >> 6][l & 63] = rb[i];
    }
    __syncthreads();
    float acc[4][4] = {{0.f}};
    int tm = (tid >> 4) * 4, tf = (tid & 15) * 4;
    #pragma unroll 8
    for (int k = 0; k < 64; k++) {
        float4 a = *(const float4*)&As[k][tm];
        float4 b = *(const float4*)&Bs[k][tf];
        acc[0][0] += a.x*b.x; acc[0][1] += a.x*b.y; acc[0][2] += a.x*b.z; acc[0][3] += a.x*b.w;
        acc[1][0] += a.y*b.x; acc[1][1] += a.y*b.y; acc[1][2] += a.y*b.z; acc[1][3] += a.y*b.w;
        acc[2][0] += a.z*b.x; acc[2][1] += a.z*b.y; acc[2][2] += a.z*b.z; acc[2][3] += a.z*b.w;
        acc[3][0] += a.w*b.x; acc[3][1] += a.w*b.y; acc[3][2] += a.w*b.z; acc[3][3] += a.w*b.w;
    }
    float* G1k = G1p + (size_t)ks * G1SZ;
    #pragma unroll
    for (int i = 0; i < 4; i++) {
        int r = r0 + tm + i;
        if (r >= 506) continue;
        int q = r >> 1, reim = r & 1;
        size_t base = (size_t)(m1*QH + q) * 128;
        #pragma unroll
        for (int j = 0; j < 4; j++)
            G1k[base + (tf + j)*2 + reim] = acc[i][j];
    }
}

// fold the 8 K-split partials
__global__ __launch_bounds__(256) void g1_reduce_kernel(const float* __restrict__ G1p,
                                                        float* __restrict__ G1) {
    int idx = blockIdx.x * 256 + threadIdx.x;
    if (idx >= G1SZ/4) return;
    const float4* p = (const float4*)G1p;
    float4 s = p[idx];
    #pragma unroll
    for (int ks = 1; ks < G1KS; ks++) {
        float4 v = p[(size_t)ks*(G1SZ/4) + idx];
        s.x += v.x; s.y += v.y; s.z += v.z; s.w += v.w;
    }
    ((float4*)G1)[idx] = s;
}

// Gmat[2t..2t+1][f] from G1: fold 9-point DFT over m1, Hermitian weight, 1/4545
__global__ __launch_bounds__(64) void gmat_kernel(const float* __restrict__ G1,
                                                  const float* __restrict__ wp,
                                                  float* __restrict__ Gmat) {
    int t = blockIdx.x;
    int f = threadIdx.x;
    if (t >= THALF) {
        Gmat[(size_t)(2*t)*FD + f] = 0.f;
        Gmat[(size_t)(2*t+1)*FD + f] = 0.f;
        return;
    }
    int p, q;
    if (t < QH) { p = 0; q = t; }
    else { int u = t - QH; p = 1 + u / M2D; q = u % M2D; }
    float gr = 0.f, gi = 0.f;
    #pragma unroll
    for (int m1 = 0; m1 < M1D; m1++) {
        float ar, ai;
        if (q < QH) { size_t o = ((size_t)(m1*QH + q)*FD + f)*2; ar = G1[o]; ai = G1[o+1]; }
        else        { size_t o = ((size_t)(m1*QH + (M2D - q))*FD + f)*2; ar = G1[o]; ai = -G1[o+1]; }
        int pm = (p * m1) % M1D;
        float cr = wp[2*pm], ci = -wp[2*pm+1];
        gr += ar*cr - ai*ci;
        gi += ar*ci + ai*cr;
    }
    float scale = (t == 0) ? (1.0f/4545.0f) : (2.0f/4545.0f);
    Gmat[(size_t)(2*t)*FD + f]   =  gr * scale;
    Gmat[(size_t)(2*t+1)*FD + f] = -gi * scale;
}

// one block (256 thr) per node. Round-12: reverted to in-kernel float2 Z-pass
// (round-11's 64-block z_kernel was occupancy-starved — 55 barrier-separated
// sort stages on 1/4 of the CUs cost more than the 67M-exp pass it replaced).
__global__ __launch_bounds__(256) void attn_agg_kernel(const float* __restrict__ x,
                                                       const float* __restrict__ adj,
                                                       const float* __restrict__ xl,
                                                       const float* __restrict__ xr,
                                                       const float* __restrict__ sumx,
                                                       float* __restrict__ agg) {
    int node = blockIdx.x;
    int b = node >> 10;
    int tid = threadIdx.x;
    __shared__ float xr_s[CH], Zinv[CH], Sinv[CH];
    __shared__ float red16[16][CH];
    __shared__ int act_list[NN + 8];
    __shared__ int act_n;
    __shared__ float qv2[64][CH];

    if (tid < CH) xr_s[tid] = xr[(size_t)node*CH + tid];
    if (tid == 0) act_n = 0;
    __syncthreads();

    int c = tid & 31, jl = tid >> 5;
    const float* xlb = xl + ((size_t)b << 10) * CH;
    const float* adjrow = adj + (size_t)node * NN;

    // Z-pass: float2 per thread (c-pair), 8 outer x 8 independent loads
    int c2 = tid & 15, jl16 = tid >> 4;
    const float2* xlb2 = (const float2*)xlb;
    float xrcx = xr_s[2*c2], xrcy = xr_s[2*c2+1];
    float zx = 0.f, zy = 0.f;
    for (int j0 = jl16; j0 < NN; j0 += 128) {
        float2 sv[8];
        #pragma unroll
        for (int u = 0; u < 8; u++) sv[u] = xlb2[(size_t)(j0 + u*16)*16 + c2];
        #pragma unroll
        for (int u = 0; u < 8; u++) {
            float s0 = sv[u].x + xrcx; s0 = s0 > 0.f ? s0 : 0.01f * s0;
            float s1 = sv[u].y + xrcy; s1 = s1 > 0.f ? s1 : 0.01f * s1;
            zx += __expf(s0); zy += __expf(s1);
        }
    }
    red16[jl16][2*c2]   = zx;
    red16[jl16][2*c2+1] = zy;

    // active-list scan (4 batched loads per thread)
    float av[4];
    #pragma unroll
    for (int u = 0; u < 4; u++) av[u] = adjrow[tid + u*256];
    __syncthreads();
    if (tid < CH) {
        float z = 0.f;
        #pragma unroll
        for (int r = 0; r < 16; r++) z += red16[r][tid];
        Zinv[tid] = FRCP(z);
    }
    #pragma unroll
    for (int u = 0; u < 4; u++)
        if (av[u] != 0.f) { int p = atomicAdd(&act_n, 1); act_list[p] = tid + u*256; }
    __syncthreads();
    int nact = act_n;

    int f = tid & 63, n0 = tid >> 6;
    int g = f >> 4;
    int c0 = n0*4 + g, c1 = (n0+4)*4 + g;
    const float* xb = x + ((size_t)b << 10) * FD;
    float acc0 = 0.f, acc1 = 0.f, sacc = 0.f;

    for (int base = 0; base < nact; base += 64) {
        int cnt = min(64, nact - base);
        int cntp = (cnt + 7) & ~7;
        for (int u = tid; u < (cnt << 5); u += 256) {
            int jj = u >> 5, cc = u & 31;
            int j = act_list[base + jj];
            float s = xlb[j*CH + cc] + xr_s[cc];
            s = s > 0.f ? s : 0.01f * s;
            float pv = __expf(s) * Zinv[cc];
            float qq = fmaxf(pv, 1e-6f) - 1e-6f;
            qv2[jj][cc] = qq;
            sacc += qq;
        }
        for (int u = tid + (cnt << 5); u < (cntp << 5); u += 256)
            qv2[u >> 5][u & 31] = 0.f;
        if (tid < cntp - cnt) act_list[base + cnt + tid] = act_list[base];
        __syncthreads();
        for (int jb = 0; jb < cntp; jb += 8) {
            float xv[8];
            #pragma unroll
            for (int u = 0; u < 8; u++) xv[u] = xb[act_list[base + jb + u]*FD + f];
            #pragma unroll
            for (int u = 0; u < 8; u++) {
                acc0 += qv2[jb+u][c0] * xv[u];
                acc1 += qv2[jb+u][c1] * xv[u];
            }
        }
        __syncthreads();
    }
    red16[jl][c] = sacc;
    __syncthreads();
    if (tid < CH) {
        float s = 0.f;
        #pragma unroll
        for (int r = 0; r < 8; r++) s += red16[r][tid];
        Sinv[tid] = FRCP(s + (float)NN * 1e-6f);
    }
    __syncthreads();
    float sx = sumx[b*FD + f] * 1e-6f;
    agg[(size_t)node*512 + n0*FD + f]       = (acc0 + sx) * Sinv[c0];
    agg[(size_t)node*512 + (n0+4)*FD + f]   = (acc1 + sx) * Sinv[c1];
}

// A2 = agg @ Wt : [16384 x 64] @ [64 x 512]. grid (256 mtiles, 8 ntiles)
__global__ __launch_bounds__(256) void a_gemm_kernel(const float* __restrict__ agg,
                                                     const float* __restrict__ Wt,
                                                     float* __restrict__ A2) {
    int mt = blockIdx.x, nt = blockIdx.y;
    int tid = threadIdx.x;
    __shared__ float As2[64][68];
    __shared__ float Bs[64][64];
    float acc[4][4] = {{0.f}};
    int tm = (tid >> 4) * 4, tf = (tid & 15) * 4;
    float ra[16], rb[16];
    #pragma unroll
    for (int i = 0; i < 16; i++) {
        int l = tid + i*256;
        int r = l >> 6, k = l & 63;
        ra[i] = agg[(size_t)(mt*64 + r)*64 + k];
    }
    #pragma unroll
    for (int i = 0; i < 16; i++) {
        int l = tid + i*256;
        int k = l >> 6, cc = l & 63;
        rb[i] = Wt[(size_t)k*512 + nt*64 + cc];
    }
    #pragma unroll
    for (int i = 0; i < 16; i++) {
        int l = tid + i*256;
        As2[l & 63][l >> 6] = ra[i];
    }
    #pragma unroll
    for (int i = 0; i < 16; i++) {
        int l = tid + i*256;
        Bs[l >> 6][l & 63] = rb[i];
    }
    __syncthreads();
    #pragma unroll 8
    for (int k = 0; k < 64; k++) {
        float4 a = *(const float4*)&As2[k][tm];
        float4 b = *(const float4*)&Bs[k][tf];
        acc[0][0] += a.x*b.x; acc[0][1] += a.x*b.y; acc[0][2] += a.x*b.z; acc[0][3] += a.x*b.w;
        acc[1][0] += a.y*b.x; acc[1][1] += a.y*b.y; acc[1][2] += a.y*b.z; acc[1][3] += a.y*b.w;
        acc[2][0] += a.z*b.x; acc[2][1] += a.z*b.y; acc[2][2] += a.z*b.z; acc[2][3] += a.z*b.w;
        acc[3][0] += a.w*b.x; acc[3][1] += a.w*b.y; acc[3][2] += a.w*b.z; acc[3][3] += a.w*b.w;
    }
    #pragma unroll
    for (int i = 0; i < 4; i++) {
        float4 v = make_float4(acc[i][0], acc[i][1], acc[i][2], acc[i][3]);
        *(float4*)&A2[(size_t)(mt*64 + tm + i)*512 + nt*64 + tf] = v;
    }
}

// one block (256 thr) per node: Y half-grid from A2.
__global__ __launch_bounds__(256) void y_kernel(const float* __restrict__ A2,
                                                float* __restrict__ Y) {
    int node = blockIdx.x;
    int tid = threadIdx.x;
    __shared__ float2 AL[8][QH];

    const float2* A2c = (const float2*)(A2 + (size_t)(node*8)*512);
    float2 rl[8];
    #pragma unroll
    for (int i = 0; i < 8; i++) {
        int idx = tid + i*256;
        rl[i] = (idx < 8*QH) ? A2c[(idx/QH)*256 + (idx%QH)] : make_float2(0.f, 0.f);
    }
    #pragma unroll
    for (int i = 0; i < 8; i++) {
        int idx = tid + i*256;
        if (idx < 8*QH) AL[idx/QH][idx%QH] = rl[i];
    }
    __syncthreads();

    float* Yrow = Y + (size_t)node * KPAD;
    if (tid < KPAD - 2*THALF) Yrow[2*THALF + tid] = 0.f;

    const float CPt[5] = {1.0f, 0.766044443119f, 0.173648177667f, -0.5f, -0.939692620786f};
    const float SPt[5] = {0.0f, -0.642787609687f, -0.984807753012f, -0.866025403784f, -0.342020143326f};

    #define Y_BODY(P, Q, QQ, CSIGN)                                            \
    {                                                                          \
        float cp = CPt[P], sp = SPt[P];                                        \
        float Pr = 1.f, Pi = 0.f, rp2 = 1.f;                                   \
        _Pragma("unroll")                                                      \
        for (int n = 0; n < 8; n++) {                                          \
            float2 Av = AL[n][QQ];                                             \
            float Ar = Av.x, Ai = (CSIGN) * Av.y;                              \
            float Xr = cp - Ar, Xi = sp - Ai;                                  \
            rp2 *= (Xr*Xr + Xi*Xi);                                            \
            float nPr = Pr*Xr - Pi*Xi;                                         \
            Pi = Pr*Xi + Pi*Xr; Pr = nPr;                                      \
        }                                                                      \
        float pAbs = FSQRT(Pr*Pr + Pi*Pi);                                     \
        float rp8 = FSQRT(FSQRT(FSQRT(FSQRT(rp2))));                           \
        float s = rp8 * FRCP(fmaxf(pAbs, 1e-20f));                             \
        int t = (P == 0) ? (Q) : (QH + ((P)-1)*M2D + (Q));                     \
        *(float2*)&Yrow[2*t] = make_float2(s*Pr, s*Pi);                        \
    }

    if (tid < QH) Y_BODY(0, tid, tid, 1.f);
    #pragma unroll
    for (int p = 1; p <= 4; p++) {
        {
            int q = tid;
            int qq = (q < QH) ? q : (M2D - q);
            float cs = (q < QH) ? 1.f : -1.f;
            Y_BODY(p, q, qq, cs);
        }
        {
            int q = tid + 256;
            if (q < M2D) {
                int qq = M2D - q;
                Y_BODY(p, q, qq, -1.f);
            }
        }
    }
    #undef Y_BODY
}

// partials[kc] = Y[:, kc-chunk] @ Gmat[kc-chunk, :] ; grid (32 Mtiles, 24 kc)
__global__ __launch_bounds__(256) void gemm_kernel(const float* __restrict__ Y,
                                                   const float* __restrict__ Gmat,
                                                   float* __restrict__ part) {
    int mtile = blockIdx.x, kc = blockIdx.y;
    int tid = threadIdx.x;
    __shared__ float Yt2[32][68];
    __shared__ float Gt[32][64];
    int m0 = mtile * 64;
    int k0 = kc * KCHUNK;
    float acc[4][4] = {{0.f}};
    int tm = (tid >> 4) * 4;
    int tf = (tid & 15) * 4;
    float ra[8], rb[8];
    #pragma unroll
    for (int i = 0; i < 8; i++) {
        int l = tid + i*256;
        int r = l >> 5, kk = l & 31;
        ra[i] = Y[(size_t)(m0 + r)*KPAD + k0 + kk];
    }
    #pragma unroll
    for (int i = 0; i < 8; i++) {
        int l = tid + i*256;
        int kk = l >> 6, cc = l & 63;
        rb[i] = Gmat[(size_t)(k0 + kk)*FD + cc];
    }
    for (int ks = 0; ks < KCHUNK; ks += 32) {
        #pragma unroll
        for (int i = 0; i < 8; i++) {
            int l = tid + i*256;
            Yt2[l & 31][l >> 5] = ra[i];
        }
        #pragma unroll
        for (int i = 0; i < 8; i++) {
            int l = tid + i*256;
            Gt[l >> 6][l & 63] = rb[i];
        }
        __syncthreads();
        if (ks + 32 < KCHUNK) {
            int kn = k0 + ks + 32;
            #pragma unroll
            for (int i = 0; i < 8; i++) {
                int l = tid + i*256;
                int r = l >> 5, kk = l & 31;
                ra[i] = Y[(size_t)(m0 + r)*KPAD + kn + kk];
            }
            #pragma unroll
            for (int i = 0; i < 8; i++) {
                int l = tid + i*256;
                int kk = l >> 6, cc = l & 63;
                rb[i] = Gmat[(size_t)(kn + kk)*FD + cc];
            }
        }
        #pragma unroll 8
        for (int k = 0; k < 32; k++) {
            float4 a = *(const float4*)&Yt2[k][tm];
            float4 b = *(const float4*)&Gt[k][tf];
            acc[0][0] += a.x*b.x; acc[0][1] += a.x*b.y; acc[0][2] += a.x*b.z; acc[0][3] += a.x*b.w;
            acc[1][0] += a.y*b.x; acc[1][1] += a.y*b.y; acc[1][2] += a.y*b.z; acc[1][3] += a.y*b.w;
            acc[2][0] += a.z*b.x; acc[2][1] += a.z*b.y; acc[2][2] += a.z*b.z; acc[2][3] += a.z*b.w;
            acc[3][0] += a.w*b.x; acc[3][1] += a.w*b.y; acc[3][2] += a.w*b.z; acc[3][3] += a.w*b.w;
        }
        __syncthreads();
    }
    float* prow = part + (size_t)kc * (2048*FD);
    #pragma unroll
    for (int i = 0; i < 4; i++) {
        float4 v = make_float4(acc[i][0], acc[i][1], acc[i][2], acc[i][3]);
        *(float4*)&prow[(size_t)(m0 + tm + i)*FD + tf] = v;
    }
}

// sum 24 partials + bias + mask -> out
__global__ __launch_bounds__(256) void reduce_kernel(const float* __restrict__ part,
                                                     const float* __restrict__ bm,
                                                     const float* __restrict__ mask,
                                                     float* __restrict__ out) {
    int idx = blockIdx.x * 256 + threadIdx.x;
    if (idx >= 32768) return;
    const float4* p4 = (const float4*)part;
    float4 s = p4[idx];
    #pragma unroll
    for (int kc = 1; kc < KSPLIT; kc++) {
        float4 v = p4[(size_t)kc*32768 + idx];
        s.x += v.x; s.y += v.y; s.z += v.z; s.w += v.w;
    }
    int f0 = (idx & 15) * 4;
    int node = idx >> 4;
    float mk = mask[node];
    s.x = (s.x + bm[f0])   * mk;
    s.y = (s.y + bm[f0+1]) * mk;
    s.z = (s.z + bm[f0+2]) * mk;
    s.w = (s.w + bm[f0+3]) * mk;
    ((float4*)out)[idx] = s;
}

extern "C" void kernel_launch(void* const* d_in, const int* in_sizes, int n_in,
                              void* d_out, int out_size, void* d_ws, size_t ws_size,
                              hipStream_t stream) {
    const float* x    = (const float*)d_in[0];
    const float* adj  = (const float*)d_in[1];
    const float* mask = (const float*)d_in[2];
    const float* Wl   = (const float*)d_in[3];
    const float* bl   = (const float*)d_in[4];
    const float* Wr   = (const float*)d_in[5];
    const float* br   = (const float*)d_in[6];
    const float* Wm   = (const float*)d_in[9];
    const float* bm   = (const float*)d_in[10];
    float* out = (float*)d_out;
    float* ws  = (float*)d_ws;

    float* wp   = ws + OFF_WP;
    float* sumx = ws + OFF_SUMX;
    float* G1   = ws + OFF_G1;
    float* Gmat = ws + OFF_GMAT;
    float* xl   = ws + OFF_XL;
    float* xr   = ws + OFF_XR;
    float* agg  = ws + OFF_AGG;
    float* part = ws + OFF_PART;
    float* T    = ws + OFF_Y;     // alias: T dead before y_kernel writes Y
    float* Y    = ws + OFF_Y;
    float* A2   = ws + OFF_A2;
    float* Wt   = ws + OFF_WT;
    float* G1p  = ws + OFF_G1P;

    hipLaunchKernelGGL(build_tw_kernel, dim3((506*512 + 64*512 + 255)/256), dim3(256), 0, stream, T, Wt, wp, sumx);
    hipLaunchKernelGGL(proj_kernel, dim3(2080), dim3(64), 0, stream, x, Wl, bl, Wr, br, xl, xr, sumx);
    hipLaunchKernelGGL(g1_gemm_kernel, dim3(8, 9, G1KS), dim3(256), 0, stream, T, Wm, G1p);
    hipLaunchKernelGGL(g1_reduce_kernel, dim3((G1SZ/4 + 255)/256), dim3(256), 0, stream, G1p, G1);
    hipLaunchKernelGGL(gmat_kernel, dim3(KPAD/2), dim3(64), 0, stream, G1, wp, Gmat);
    hipLaunchKernelGGL(attn_agg_kernel, dim3(2048), dim3(256), 0, stream, x, adj, xl, xr, sumx, agg);
    hipLaunchKernelGGL(a_gemm_kernel, dim3(256, 8), dim3(256), 0, stream, agg, Wt, A2);
    hipLaunchKernelGGL(y_kernel, dim3(2048), dim3(256), 0, stream, A2, Y);
    hipLaunchKernelGGL(gemm_kernel, dim3(32, KSPLIT), dim3(256), 0, stream, Y, Gmat, part);
    hipLaunchKernelGGL(reduce_kernel, dim3(128), dim3(256), 0, stream, part, bm, mask, out);
}

// Round 13
// 188.870 us; speedup vs baseline: 1.1195x; 1.0892x over previous
//
#include <hip/hip_runtime.h>
#include <math.h>

#define NN 1024
#define FD 64
#define CH 32          // K*H
#define M1D 9
#define M2D 505
#define QH 253         // q in [0,252] stored
#define THALF 2273     // half-grid points
#define KPAD 4608
#define KSPLIT 16      // gemm K-split (512 blocks = 2/CU)
#define KCHUNK 288     // 4608/16 = 9*32
#define G1SZ 291456    // 9*253*64*2
#define G1KS 8         // K-split factor for g1

#define FSQRT(x) __builtin_amdgcn_sqrtf(x)
#define FRCP(x)  __builtin_amdgcn_rcpf(x)

typedef short short8 __attribute__((ext_vector_type(8)));
typedef float f32x4 __attribute__((ext_vector_type(4)));

__device__ __forceinline__ unsigned short f2bf(float x) {
    unsigned int u = __builtin_bit_cast(unsigned int, x);
    return (unsigned short)((u + 0x7FFFu + ((u >> 16) & 1u)) >> 16);
}

// ws layout (floats); ws_size = 256 MiB
#define OFF_WP    1024                    // 32
#define OFF_SUMX  1056                    // 128
#define OFF_G1    1184                    // 291456
#define OFF_GMT   292640                  // GmatT bf16 [64][4608] = 147456 floats
#define OFF_XL    440096                  // 65536
#define OFF_XR    505632                  // 65536
#define OFF_AGG   571168                  // 1048576
#define OFF_PART  1619744                 // 16*131072 = 2097152
#define OFF_Y     3716896                 // Y bf16 [2048][4608] = 4718592 floats ; first 259072 ALIASED as T
#define OFF_A2    8435488                 // 8388608
#define OFF_WT    16824096                // 32768
#define OFF_G1P   16856864                // 2331648
// total = 19,188,512 floats = 76.8 MB

// builds T and Wt via inline __sincosf; block 0 also builds wp and zeros sumx.
__global__ __launch_bounds__(256) void build_tw_kernel(float* __restrict__ T,
                                                       float* __restrict__ Wt,
                                                       float* __restrict__ wp,
                                                       float* __restrict__ sumx) {
    int idx = blockIdx.x * 256 + threadIdx.x;
    if (blockIdx.x == 0) {
        if (threadIdx.x < M1D) {
            float ang = (float)threadIdx.x * (-6.2831853f / 9.0f);
            float s, c; __sincosf(ang, &s, &c);
            wp[2*threadIdx.x] = c; wp[2*threadIdx.x+1] = s;
        }
        if (threadIdx.x >= 64 && threadIdx.x < 192) sumx[threadIdx.x - 64] = 0.f;
    }
    if (idx < 506 * 512) {
        int r = idx >> 9, m2 = idx & 511;
        float v = 0.f;
        if (m2 < M2D) {
            int q = r >> 1;
            int t = (q * m2) % M2D;
            float ang = (float)t * (-6.2831853f / 505.0f);
            float s, c; __sincosf(ang, &s, &c);
            v = (r & 1) ? -s : c;
        }
        T[idx] = v;
    } else if (idx < 506 * 512 + 64 * 512) {
        int i2 = idx - 506 * 512;
        int m = i2 >> 9, col = i2 & 511;
        float v = 0.f;
        if (col < 506) {
            int q = col >> 1;
            int t = (q * m) % M2D;
            float ang = (float)t * (-6.2831853f / 505.0f);
            float s, c; __sincosf(ang, &s, &c);
            v = (col & 1) ? s : c;
        }
        Wt[i2] = v;
    }
}

// blocks 0..2047: proj (xl/xr); blocks 2048..2079: sumx partial column sums
__global__ __launch_bounds__(64) void proj_kernel(const float* __restrict__ x,
                                                  const float* __restrict__ Wl, const float* __restrict__ bl,
                                                  const float* __restrict__ Wr, const float* __restrict__ br,
                                                  float* __restrict__ xl, float* __restrict__ xr,
                                                  float* __restrict__ sumx) {
    int blk = blockIdx.x, tid = threadIdx.x;
    if (blk >= 2048) {
        int bb = blk - 2048;
        int b = bb >> 4, chunk = bb & 15;
        const float* xb = x + (size_t)b * NN * FD;
        float acc = 0.f;
        int j0 = chunk * 64;
        #pragma unroll 4
        for (int j = j0; j < j0 + 64; j++) acc += xb[j*FD + tid];
        atomicAdd(&sumx[b*FD + tid], acc);
        return;
    }
    int node = blk;
    __shared__ float xrow[FD];
    xrow[tid] = x[(size_t)node*FD + tid];
    __syncthreads();
    int c = tid & 31;
    const float* W = (tid < 32) ? Wl : Wr;
    float acc = (tid < 32) ? bl[c] : br[c];
    #pragma unroll
    for (int f = 0; f < FD; f++) acc += xrow[f] * W[f*CH + c];
    float* dst = (tid < 32) ? xl : xr;
    dst[(size_t)node*CH + c] = acc;
}

// G1 partials: grid (8 mtiles, 9 m1, 8 ksplit), one-shot K=64 tile GEMM
__global__ __launch_bounds__(256) void g1_gemm_kernel(const float* __restrict__ T,
                                                      const float* __restrict__ Wm,
                                                      float* __restrict__ G1p) {
    int mt = blockIdx.x, m1 = blockIdx.y, ks = blockIdx.z;
    int tid = threadIdx.x;
    __shared__ float As[64][68];
    __shared__ float Bs[64][64];
    int r0 = mt * 64, k0 = ks * 64;
    const float* Wmb = Wm + (size_t)m1 * M2D * FD;
    float ra[16], rb[16];
    #pragma unroll
    for (int i = 0; i < 16; i++) {
        int l = tid + i*256;
        int r = l >> 6, k = l & 63;
        int rr = r0 + r;
        ra[i] = (rr < 506) ? T[(size_t)rr*512 + k0 + k] : 0.f;
    }
    #pragma unroll
    for (int i = 0; i < 16; i++) {
        int l = tid + i*256;
        int k = l >> 6, f = l & 63;
        int krow = k0 + k;
        rb[i] = (krow < M2D) ? Wmb[(size_t)krow*FD + f] : 0.f;
    }
    #pragma unroll
    for (int i = 0; i < 16; i++) {
        int l = tid + i*256;
        As[l & 63][l >> 6] = ra[i];
    }
    #pragma unroll
    for (int i = 0; i < 16; i++) {
        int l = tid + i*256;
        Bs[l >> 6][l & 63] = rb[i];
    }
    __syncthreads();
    float acc[4][4] = {{0.f}};
    int tm = (tid >> 4) * 4, tf = (tid & 15) * 4;
    #pragma unroll 8
    for (int k = 0; k < 64; k++) {
        float4 a = *(const float4*)&As[k][tm];
        float4 b = *(const float4*)&Bs[k][tf];
        acc[0][0] += a.x*b.x; acc[0][1] += a.x*b.y; acc[0][2] += a.x*b.z; acc[0][3] += a.x*b.w;
        acc[1][0] += a.y*b.x; acc[1][1] += a.y*b.y; acc[1][2] += a.y*b.z; acc[1][3] += a.y*b.w;
        acc[2][0] += a.z*b.x; acc[2][1] += a.z*b.y; acc[2][2] += a.z*b.z; acc[2][3] += a.z*b.w;
        acc[3][0] += a.w*b.x; acc[3][1] += a.w*b.y; acc[3][2] += a.w*b.z; acc[3][3] += a.w*b.w;
    }
    float* G1k = G1p + (size_t)ks * G1SZ;
    #pragma unroll
    for (int i = 0; i < 4; i++) {
        int r = r0 + tm + i;
        if (r >= 506) continue;
        int q = r >> 1, reim = r & 1;
        size_t base = (size_t)(m1*QH + q) * 128;
        #pragma unroll
        for (int j = 0; j < 4; j++)
            G1k[base + (tf + j)*2 + reim] = acc[i][j];
    }
}

// fold the 8 K-split partials
__global__ __launch_bounds__(256) void g1_reduce_kernel(const float* __restrict__ G1p,
                                                        float* __restrict__ G1) {
    int idx = blockIdx.x * 256 + threadIdx.x;
    if (idx >= G1SZ/4) return;
    const float4* p = (const float4*)G1p;
    float4 s = p[idx];
    #pragma unroll
    for (int ks = 1; ks < G1KS; ks++) {
        float4 v = p[(size_t)ks*(G1SZ/4) + idx];
        s.x += v.x; s.y += v.y; s.z += v.z; s.w += v.w;
    }
    ((float4*)G1)[idx] = s;
}

// GmatT bf16 [f][k]: fold 9-point DFT over m1, Hermitian weight, 1/4545.
__global__ __launch_bounds__(64) void gmat_kernel(const float* __restrict__ G1,
                                                  const float* __restrict__ wp,
                                                  unsigned short* __restrict__ GmT) {
    int t = blockIdx.x;
    int f = threadIdx.x;
    if (t >= THALF) {
        *(unsigned int*)&GmT[(size_t)f*KPAD + 2*t] = 0u;
        return;
    }
    int p, q;
    if (t < QH) { p = 0; q = t; }
    else { int u = t - QH; p = 1 + u / M2D; q = u % M2D; }
    float gr = 0.f, gi = 0.f;
    #pragma unroll
    for (int m1 = 0; m1 < M1D; m1++) {
        float ar, ai;
        if (q < QH) { size_t o = ((size_t)(m1*QH + q)*FD + f)*2; ar = G1[o]; ai = G1[o+1]; }
        else        { size_t o = ((size_t)(m1*QH + (M2D - q))*FD + f)*2; ar = G1[o]; ai = -G1[o+1]; }
        int pm = (p * m1) % M1D;
        float cr = wp[2*pm], ci = -wp[2*pm+1];
        gr += ar*cr - ai*ci;
        gi += ar*ci + ai*cr;
    }
    float scale = (t == 0) ? (1.0f/4545.0f) : (2.0f/4545.0f);
    unsigned int pk = (unsigned int)f2bf(gr*scale) | ((unsigned int)f2bf(-gi*scale) << 16);
    *(unsigned int*)&GmT[(size_t)f*KPAD + 2*t] = pk;
}

// one block (256 thr) per node: in-kernel float2 Z-pass + sparse clamped gather
__global__ __launch_bounds__(256) void attn_agg_kernel(const float* __restrict__ x,
                                                       const float* __restrict__ adj,
                                                       const float* __restrict__ xl,
                                                       const float* __restrict__ xr,
                                                       const float* __restrict__ sumx,
                                                       float* __restrict__ agg) {
    int node = blockIdx.x;
    int b = node >> 10;
    int tid = threadIdx.x;
    __shared__ float xr_s[CH], Zinv[CH], Sinv[CH];
    __shared__ float red16[16][CH];
    __shared__ int act_list[NN + 8];
    __shared__ int act_n;
    __shared__ float qv2[64][CH];

    if (tid < CH) xr_s[tid] = xr[(size_t)node*CH + tid];
    if (tid == 0) act_n = 0;
    __syncthreads();

    int c = tid & 31, jl = tid >> 5;
    const float* xlb = xl + ((size_t)b << 10) * CH;
    const float* adjrow = adj + (size_t)node * NN;

    // Z-pass: float2 per thread (c-pair), 8 outer x 8 independent loads
    int c2 = tid & 15, jl16 = tid >> 4;
    const float2* xlb2 = (const float2*)xlb;
    float xrcx = xr_s[2*c2], xrcy = xr_s[2*c2+1];
    float zx = 0.f, zy = 0.f;
    for (int j0 = jl16; j0 < NN; j0 += 128) {
        float2 sv[8];
        #pragma unroll
        for (int u = 0; u < 8; u++) sv[u] = xlb2[(size_t)(j0 + u*16)*16 + c2];
        #pragma unroll
        for (int u = 0; u < 8; u++) {
            float s0 = sv[u].x + xrcx; s0 = s0 > 0.f ? s0 : 0.01f * s0;
            float s1 = sv[u].y + xrcy; s1 = s1 > 0.f ? s1 : 0.01f * s1;
            zx += __expf(s0); zy += __expf(s1);
        }
    }
    red16[jl16][2*c2]   = zx;
    red16[jl16][2*c2+1] = zy;

    float av[4];
    #pragma unroll
    for (int u = 0; u < 4; u++) av[u] = adjrow[tid + u*256];
    __syncthreads();
    if (tid < CH) {
        float z = 0.f;
        #pragma unroll
        for (int r = 0; r < 16; r++) z += red16[r][tid];
        Zinv[tid] = FRCP(z);
    }
    #pragma unroll
    for (int u = 0; u < 4; u++)
        if (av[u] != 0.f) { int p = atomicAdd(&act_n, 1); act_list[p] = tid + u*256; }
    __syncthreads();
    int nact = act_n;

    int f = tid & 63, n0 = tid >> 6;
    int g = f >> 4;
    int c0 = n0*4 + g, c1 = (n0+4)*4 + g;
    const float* xb = x + ((size_t)b << 10) * FD;
    float acc0 = 0.f, acc1 = 0.f, sacc = 0.f;

    for (int base = 0; base < nact; base += 64) {
        int cnt = min(64, nact - base);
        int cntp = (cnt + 7) & ~7;
        for (int u = tid; u < (cnt << 5); u += 256) {
            int jj = u >> 5, cc = u & 31;
            int j = act_list[base + jj];
            float s = xlb[j*CH + cc] + xr_s[cc];
            s = s > 0.f ? s : 0.01f * s;
            float pv = __expf(s) * Zinv[cc];
            float qq = fmaxf(pv, 1e-6f) - 1e-6f;
            qv2[jj][cc] = qq;
            sacc += qq;
        }
        for (int u = tid + (cnt << 5); u < (cntp << 5); u += 256)
            qv2[u >> 5][u & 31] = 0.f;
        if (tid < cntp - cnt) act_list[base + cnt + tid] = act_list[base];
        __syncthreads();
        for (int jb = 0; jb < cntp; jb += 8) {
            float xv[8];
            #pragma unroll
            for (int u = 0; u < 8; u++) xv[u] = xb[act_list[base + jb + u]*FD + f];
            #pragma unroll
            for (int u = 0; u < 8; u++) {
                acc0 += qv2[jb+u][c0] * xv[u];
                acc1 += qv2[jb+u][c1] * xv[u];
            }
        }
        __syncthreads();
    }
    red16[jl][c] = sacc;
    __syncthreads();
    if (tid < CH) {
        float s = 0.f;
        #pragma unroll
        for (int r = 0; r < 8; r++) s += red16[r][tid];
        Sinv[tid] = FRCP(s + (float)NN * 1e-6f);
    }
    __syncthreads();
    float sx = sumx[b*FD + f] * 1e-6f;
    agg[(size_t)node*512 + n0*FD + f]       = (acc0 + sx) * Sinv[c0];
    agg[(size_t)node*512 + (n0+4)*FD + f]   = (acc1 + sx) * Sinv[c1];
}

// A2 = agg @ Wt : [16384 x 64] @ [64 x 512]. grid (256 mtiles, 8 ntiles)
__global__ __launch_bounds__(256) void a_gemm_kernel(const float* __restrict__ agg,
                                                     const float* __restrict__ Wt,
                                                     float* __restrict__ A2) {
    int mt = blockIdx.x, nt = blockIdx.y;
    int tid = threadIdx.x;
    __shared__ float As2[64][68];
    __shared__ float Bs[64][64];
    float acc[4][4] = {{0.f}};
    int tm = (tid >> 4) * 4, tf = (tid & 15) * 4;
    float ra[16], rb[16];
    #pragma unroll
    for (int i = 0; i < 16; i++) {
        int l = tid + i*256;
        int r = l >> 6, k = l & 63;
        ra[i] = agg[(size_t)(mt*64 + r)*64 + k];
    }
    #pragma unroll
    for (int i = 0; i < 16; i++) {
        int l = tid + i*256;
        int k = l >> 6, cc = l & 63;
        rb[i] = Wt[(size_t)k*512 + nt*64 + cc];
    }
    #pragma unroll
    for (int i = 0; i < 16; i++) {
        int l = tid + i*256;
        As2[l & 63][l >> 6] = ra[i];
    }
    #pragma unroll
    for (int i = 0; i < 16; i++) {
        int l = tid + i*256;
        Bs[l >> 6][l & 63] = rb[i];
    }
    __syncthreads();
    #pragma unroll 8
    for (int k = 0; k < 64; k++) {
        float4 a = *(const float4*)&As2[k][tm];
        float4 b = *(const float4*)&Bs[k][tf];
        acc[0][0] += a.x*b.x; acc[0][1] += a.x*b.y; acc[0][2] += a.x*b.z; acc[0][3] += a.x*b.w;
        acc[1][0] += a.y*b.x; acc[1][1] += a.y*b.y; acc[1][2] += a.y*b.z; acc[1][3] += a.y*b.w;
        acc[2][0] += a.z*b.x; acc[2][1] += a.z*b.y; acc[2][2] += a.z*b.z; acc[2][3] += a.z*b.w;
        acc[3][0] += a.w*b.x; acc[3][1] += a.w*b.y; acc[3][2] += a.w*b.z; acc[3][3] += a.w*b.w;
    }
    #pragma unroll
    for (int i = 0; i < 4; i++) {
        float4 v = make_float4(acc[i][0], acc[i][1], acc[i][2], acc[i][3]);
        *(float4*)&A2[(size_t)(mt*64 + tm + i)*512 + nt*64 + tf] = v;
    }
}

// one block (256 thr) per node: Y half-grid from A2, written as bf16.
__global__ __launch_bounds__(256) void y_kernel(const float* __restrict__ A2,
                                                unsigned short* __restrict__ Yb) {
    int node = blockIdx.x;
    int tid = threadIdx.x;
    __shared__ float2 AL[8][QH];

    const float2* A2c = (const float2*)(A2 + (size_t)(node*8)*512);
    float2 rl[8];
    #pragma unroll
    for (int i = 0; i < 8; i++) {
        int idx = tid + i*256;
        rl[i] = (idx < 8*QH) ? A2c[(idx/QH)*256 + (idx%QH)] : make_float2(0.f, 0.f);
    }
    #pragma unroll
    for (int i = 0; i < 8; i++) {
        int idx = tid + i*256;
        if (idx < 8*QH) AL[idx/QH][idx%QH] = rl[i];
    }
    __syncthreads();

    unsigned short* Yrow = Yb + (size_t)node * KPAD;
    if (tid < (KPAD - 2*THALF)/2) *(unsigned int*)&Yrow[2*THALF + 2*tid] = 0u;

    const float CPt[5] = {1.0f, 0.766044443119f, 0.173648177667f, -0.5f, -0.939692620786f};
    const float SPt[5] = {0.0f, -0.642787609687f, -0.984807753012f, -0.866025403784f, -0.342020143326f};

    #define Y_BODY(P, Q, QQ, CSIGN)                                            \
    {                                                                          \
        float cp = CPt[P], sp = SPt[P];                                        \
        float Pr = 1.f, Pi = 0.f, rp2 = 1.f;                                   \
        _Pragma("unroll")                                                      \
        for (int n = 0; n < 8; n++) {                                          \
            float2 Av = AL[n][QQ];                                             \
            float Ar = Av.x, Ai = (CSIGN) * Av.y;                              \
            float Xr = cp - Ar, Xi = sp - Ai;                                  \
            rp2 *= (Xr*Xr + Xi*Xi);                                            \
            float nPr = Pr*Xr - Pi*Xi;                                         \
            Pi = Pr*Xi + Pi*Xr; Pr = nPr;                                      \
        }                                                                      \
        float pAbs = FSQRT(Pr*Pr + Pi*Pi);                                     \
        float rp8 = FSQRT(FSQRT(FSQRT(FSQRT(rp2))));                           \
        float s = rp8 * FRCP(fmaxf(pAbs, 1e-20f));                             \
        int t = (P == 0) ? (Q) : (QH + ((P)-1)*M2D + (Q));                     \
        unsigned int pk = (unsigned int)f2bf(s*Pr) | ((unsigned int)f2bf(s*Pi) << 16); \
        *(unsigned int*)&Yrow[2*t] = pk;                                       \
    }

    if (tid < QH) Y_BODY(0, tid, tid, 1.f);
    #pragma unroll
    for (int p = 1; p <= 4; p++) {
        {
            int q = tid;
            int qq = (q < QH) ? q : (M2D - q);
            float cs = (q < QH) ? 1.f : -1.f;
            Y_BODY(p, q, qq, cs);
        }
        {
            int q = tid + 256;
            if (q < M2D) {
                int qq = M2D - q;
                Y_BODY(p, q, qq, -1.f);
            }
        }
    }
    #undef Y_BODY
}

// MFMA bf16 gemm: part[kc] += Y[:, kc] @ GmatT^T ; grid (32 mtiles, 16 kc).
// Wave w owns n-tile w (16 cols), 4 C-frags over the 4 m-tiles.
// A-frag A[m=lane&15][k=quad*8+j]; B-frag from GmT LDS (n-major);
// C/D: col=lane&15 (=n), row=quad*4+reg (=m)  [guide-verified layouts].
__global__ __launch_bounds__(256) void gemm_kernel(const unsigned short* __restrict__ Yb,
                                                   const unsigned short* __restrict__ GmT,
                                                   float* __restrict__ part) {
    int mtile = blockIdx.x, kc = blockIdx.y;
    int tid = threadIdx.x;
    __shared__ unsigned short Ys[64*40];   // [m][k], stride 40 bf16 (80 B, 2-way-free)
    __shared__ unsigned short Gs[64*40];   // [n][k], stride 40
    int m0 = mtile * 64;
    int k0 = kc * KCHUNK;
    int r = tid >> 2, kg = (tid & 3) * 8;
    const unsigned short* Ysrc = Yb + (size_t)(m0 + r)*KPAD + k0 + kg;
    const unsigned short* Gsrc = GmT + (size_t)r*KPAD + k0 + kg;
    uint4 ya = *(const uint4*)Ysrc;
    uint4 ga = *(const uint4*)Gsrc;
    int w = tid >> 6, lane = tid & 63;
    int lm = lane & 15, quad = lane >> 4;
    f32x4 acc0 = {0.f,0.f,0.f,0.f}, acc1 = acc0, acc2 = acc0, acc3 = acc0;
    for (int ks = 0; ks < KCHUNK; ks += 32) {
        *(uint4*)&Ys[r*40 + kg] = ya;
        *(uint4*)&Gs[r*40 + kg] = ga;
        __syncthreads();
        if (ks + 32 < KCHUNK) {
            ya = *(const uint4*)(Ysrc + ks + 32);
            ga = *(const uint4*)(Gsrc + ks + 32);
        }
        short8 b  = *(const short8*)&Gs[(w*16 + lm)*40 + quad*8];
        short8 a0 = *(const short8*)&Ys[(lm)*40      + quad*8];
        short8 a1 = *(const short8*)&Ys[(16 + lm)*40 + quad*8];
        short8 a2 = *(const short8*)&Ys[(32 + lm)*40 + quad*8];
        short8 a3 = *(const short8*)&Ys[(48 + lm)*40 + quad*8];
        acc0 = __builtin_amdgcn_mfma_f32_16x16x32_bf16(a0, b, acc0, 0, 0, 0);
        acc1 = __builtin_amdgcn_mfma_f32_16x16x32_bf16(a1, b, acc1, 0, 0, 0);
        acc2 = __builtin_amdgcn_mfma_f32_16x16x32_bf16(a2, b, acc2, 0, 0, 0);
        acc3 = __builtin_amdgcn_mfma_f32_16x16x32_bf16(a3, b, acc3, 0, 0, 0);
        __syncthreads();
    }
    float* prow = part + (size_t)kc * (2048*FD);
    int col = w*16 + lm;
    #pragma unroll
    for (int rr = 0; rr < 4; rr++) {
        int row = quad*4 + rr;
        prow[(size_t)(m0 + row)*FD + col]      = acc0[rr];
        prow[(size_t)(m0 + 16 + row)*FD + col] = acc1[rr];
        prow[(size_t)(m0 + 32 + row)*FD + col] = acc2[rr];
        prow[(size_t)(m0 + 48 + row)*FD + col] = acc3[rr];
    }
}

// sum 16 partials + bias + mask -> out
__global__ __launch_bounds__(256) void reduce_kernel(const float* __restrict__ part,
                                                     const float* __restrict__ bm,
                                                     const float* __restrict__ mask,
                                                     float* __restrict__ out) {
    int idx = blockIdx.x * 256 + threadIdx.x;
    if (idx >= 32768) return;
    const float4* p4 = (const float4*)part;
    float4 s = p4[idx];
    #pragma unroll
    for (int kc = 1; kc < KSPLIT; kc++) {
        float4 v = p4[(size_t)kc*32768 + idx];
        s.x += v.x; s.y += v.y; s.z += v.z; s.w += v.w;
    }
    int f0 = (idx & 15) * 4;
    int node = idx >> 4;
    float mk = mask[node];
    s.x = (s.x + bm[f0])   * mk;
    s.y = (s.y + bm[f0+1]) * mk;
    s.z = (s.z + bm[f0+2]) * mk;
    s.w = (s.w + bm[f0+3]) * mk;
    ((float4*)out)[idx] = s;
}

extern "C" void kernel_launch(void* const* d_in, const int* in_sizes, int n_in,
                              void* d_out, int out_size, void* d_ws, size_t ws_size,
                              hipStream_t stream) {
    const float* x    = (const float*)d_in[0];
    const float* adj  = (const float*)d_in[1];
    const float* mask = (const float*)d_in[2];
    const float* Wl   = (const float*)d_in[3];
    const float* bl   = (const float*)d_in[4];
    const float* Wr   = (const float*)d_in[5];
    const float* br   = (const float*)d_in[6];
    const float* Wm   = (const float*)d_in[9];
    const float* bm   = (const float*)d_in[10];
    float* out = (float*)d_out;
    float* ws  = (float*)d_ws;

    float* wp   = ws + OFF_WP;
    float* sumx = ws + OFF_SUMX;
    float* G1   = ws + OFF_G1;
    unsigned short* GmT = (unsigned short*)(ws + OFF_GMT);
    float* xl   = ws + OFF_XL;
    float* xr   = ws + OFF_XR;
    float* agg  = ws + OFF_AGG;
    float* part = ws + OFF_PART;
    float* T    = ws + OFF_Y;     // alias: T dead before y_kernel writes Yb
    unsigned short* Yb = (unsigned short*)(ws + OFF_Y);
    float* A2   = ws + OFF_A2;
    float* Wt   = ws + OFF_WT;
    float* G1p  = ws + OFF_G1P;

    hipLaunchKernelGGL(build_tw_kernel, dim3((506*512 + 64*512 + 255)/256), dim3(256), 0, stream, T, Wt, wp, sumx);
    hipLaunchKernelGGL(proj_kernel, dim3(2080), dim3(64), 0, stream, x, Wl, bl, Wr, br, xl, xr, sumx);
    hipLaunchKernelGGL(g1_gemm_kernel, dim3(8, 9, G1KS), dim3(256), 0, stream, T, Wm, G1p);
    hipLaunchKernelGGL(g1_reduce_kernel, dim3((G1SZ/4 + 255)/256), dim3(256), 0, stream, G1p, G1);
    hipLaunchKernelGGL(gmat_kernel, dim3(KPAD/2), dim3(64), 0, stream, G1, wp, GmT);
    hipLaunchKernelGGL(attn_agg_kernel, dim3(2048), dim3(256), 0, stream, x, adj, xl, xr, sumx, agg);
    hipLaunchKernelGGL(a_gemm_kernel, dim3(256, 8), dim3(256), 0, stream, agg, Wt, A2);
    hipLaunchKernelGGL(y_kernel, dim3(2048), dim3(256), 0, stream, A2, Yb);
    hipLaunchKernelGGL(gemm_kernel, dim3(32, KSPLIT), dim3(256), 0, stream, Yb, GmT, part);
    hipLaunchKernelGGL(reduce_kernel, dim3(128), dim3(256), 0, stream, part, bm, mask, out);
}

// Round 14
// 176.961 us; speedup vs baseline: 1.1948x; 1.0673x over previous
//
#include <hip/hip_runtime.h>
#include <math.h>

#define NN 1024
#define FD 64
#define CH 32          // K*H
#define M1D 9
#define M2D 505
#define QH 253         // q in [0,252] stored
#define THALF 2273     // half-grid points
#define KPAD 4608
#define KSPLIT 16      // gemm K-split (512 blocks = 2/CU)
#define KCHUNK 288     // 4608/16 = 9*32
#define G1SZ 291456    // 9*253*64*2
#define G1KS 8         // K-split factor for g1

#define FSQRT(x) __builtin_amdgcn_sqrtf(x)
#define FRCP(x)  __builtin_amdgcn_rcpf(x)

typedef short short8 __attribute__((ext_vector_type(8)));
typedef float f32x4 __attribute__((ext_vector_type(4)));

__device__ __forceinline__ unsigned short f2bf(float x) {
    unsigned int u = __builtin_bit_cast(unsigned int, x);
    return (unsigned short)((u + 0x7FFFu + ((u >> 16) & 1u)) >> 16);
}

// ws layout (floats); ws_size = 256 MiB
#define OFF_WP    1024                    // 32
#define OFF_SUMX  1056                    // 128
#define OFF_GMT   1184                    // GmatT bf16 [64][4608] = 147456 floats
#define OFF_XL    148640                  // 65536
#define OFF_XR    214176                  // 65536
#define OFF_AGG   279712                  // 1048576
#define OFF_PART  1328288                 // 16*131072 = 2097152
#define OFF_Y     3425440                 // Y bf16 [2048][4608] = 4718592 floats ; first 259072 ALIASED as T
#define OFF_WT    8144032                 // 32768
#define OFF_G1P   8176800                 // 8*291456 = 2331648
// total = 10,508,448 floats = 42.0 MB

// builds T and Wt via inline __sincosf; block 0 also builds wp and zeros sumx.
__global__ __launch_bounds__(256) void build_tw_kernel(float* __restrict__ T,
                                                       float* __restrict__ Wt,
                                                       float* __restrict__ wp,
                                                       float* __restrict__ sumx) {
    int idx = blockIdx.x * 256 + threadIdx.x;
    if (blockIdx.x == 0) {
        if (threadIdx.x < M1D) {
            float ang = (float)threadIdx.x * (-6.2831853f / 9.0f);
            float s, c; __sincosf(ang, &s, &c);
            wp[2*threadIdx.x] = c; wp[2*threadIdx.x+1] = s;
        }
        if (threadIdx.x >= 64 && threadIdx.x < 192) sumx[threadIdx.x - 64] = 0.f;
    }
    if (idx < 506 * 512) {
        int r = idx >> 9, m2 = idx & 511;
        float v = 0.f;
        if (m2 < M2D) {
            int q = r >> 1;
            int t = (q * m2) % M2D;
            float ang = (float)t * (-6.2831853f / 505.0f);
            float s, c; __sincosf(ang, &s, &c);
            v = (r & 1) ? -s : c;
        }
        T[idx] = v;
    } else if (idx < 506 * 512 + 64 * 512) {
        int i2 = idx - 506 * 512;
        int m = i2 >> 9, col = i2 & 511;
        float v = 0.f;
        if (col < 506) {
            int q = col >> 1;
            int t = (q * m) % M2D;
            float ang = (float)t * (-6.2831853f / 505.0f);
            float s, c; __sincosf(ang, &s, &c);
            v = (col & 1) ? s : c;
        }
        Wt[i2] = v;
    }
}

// blocks 0..2047: proj (xl/xr); blocks 2048..2079: sumx partial column sums
__global__ __launch_bounds__(64) void proj_kernel(const float* __restrict__ x,
                                                  const float* __restrict__ Wl, const float* __restrict__ bl,
                                                  const float* __restrict__ Wr, const float* __restrict__ br,
                                                  float* __restrict__ xl, float* __restrict__ xr,
                                                  float* __restrict__ sumx) {
    int blk = blockIdx.x, tid = threadIdx.x;
    if (blk >= 2048) {
        int bb = blk - 2048;
        int b = bb >> 4, chunk = bb & 15;
        const float* xb = x + (size_t)b * NN * FD;
        float acc = 0.f;
        int j0 = chunk * 64;
        #pragma unroll 4
        for (int j = j0; j < j0 + 64; j++) acc += xb[j*FD + tid];
        atomicAdd(&sumx[b*FD + tid], acc);
        return;
    }
    int node = blk;
    __shared__ float xrow[FD];
    xrow[tid] = x[(size_t)node*FD + tid];
    __syncthreads();
    int c = tid & 31;
    const float* W = (tid < 32) ? Wl : Wr;
    float acc = (tid < 32) ? bl[c] : br[c];
    #pragma unroll
    for (int f = 0; f < FD; f++) acc += xrow[f] * W[f*CH + c];
    float* dst = (tid < 32) ? xl : xr;
    dst[(size_t)node*CH + c] = acc;
}

// G1 partials: grid (8 mtiles, 9 m1, 8 ksplit), one-shot K=64 tile GEMM
__global__ __launch_bounds__(256) void g1_gemm_kernel(const float* __restrict__ T,
                                                      const float* __restrict__ Wm,
                                                      float* __restrict__ G1p) {
    int mt = blockIdx.x, m1 = blockIdx.y, ks = blockIdx.z;
    int tid = threadIdx.x;
    __shared__ float As[64][68];
    __shared__ float Bs[64][64];
    int r0 = mt * 64, k0 = ks * 64;
    const float* Wmb = Wm + (size_t)m1 * M2D * FD;
    float ra[16], rb[16];
    #pragma unroll
    for (int i = 0; i < 16; i++) {
        int l = tid + i*256;
        int r = l >> 6, k = l & 63;
        int rr = r0 + r;
        ra[i] = (rr < 506) ? T[(size_t)rr*512 + k0 + k] : 0.f;
    }
    #pragma unroll
    for (int i = 0; i < 16; i++) {
        int l = tid + i*256;
        int k = l >> 6, f = l & 63;
        int krow = k0 + k;
        rb[i] = (krow < M2D) ? Wmb[(size_t)krow*FD + f] : 0.f;
    }
    #pragma unroll
    for (int i = 0; i < 16; i++) {
        int l = tid + i*256;
        As[l & 63][l >> 6] = ra[i];
    }
    #pragma unroll
    for (int i = 0; i < 16; i++) {
        int l = tid + i*256;
        Bs[l >> 6][l & 63] = rb[i];
    }
    __syncthreads();
    float acc[4][4] = {{0.f}};
    int tm = (tid >> 4) * 4, tf = (tid & 15) * 4;
    #pragma unroll 8
    for (int k = 0; k < 64; k++) {
        float4 a = *(const float4*)&As[k][tm];
        float4 b = *(const float4*)&Bs[k][tf];
        acc[0][0] += a.x*b.x; acc[0][1] += a.x*b.y; acc[0][2] += a.x*b.z; acc[0][3] += a.x*b.w;
        acc[1][0] += a.y*b.x; acc[1][1] += a.y*b.y; acc[1][2] += a.y*b.z; acc[1][3] += a.y*b.w;
        acc[2][0] += a.z*b.x; acc[2][1] += a.z*b.y; acc[2][2] += a.z*b.z; acc[2][3] += a.z*b.w;
        acc[3][0] += a.w*b.x; acc[3][1] += a.w*b.y; acc[3][2] += a.w*b.z; acc[3][3] += a.w*b.w;
    }
    float* G1k = G1p + (size_t)ks * G1SZ;
    #pragma unroll
    for (int i = 0; i < 4; i++) {
        int r = r0 + tm + i;
        if (r >= 506) continue;
        int q = r >> 1, reim = r & 1;
        size_t base = (size_t)(m1*QH + q) * 128;
        #pragma unroll
        for (int j = 0; j < 4; j++)
            G1k[base + (tf + j)*2 + reim] = acc[i][j];
    }
}

// GmatT bf16 [f][k]: folds the 8 G1 K-split partials inline (round-14:
// g1_reduce launch removed), 9-point DFT over m1, Hermitian weight, 1/4545.
__global__ __launch_bounds__(64) void gmat_kernel(const float* __restrict__ G1p,
                                                  const float* __restrict__ wp,
                                                  unsigned short* __restrict__ GmT) {
    int t = blockIdx.x;
    int f = threadIdx.x;
    if (t >= THALF) {
        *(unsigned int*)&GmT[(size_t)f*KPAD + 2*t] = 0u;
        return;
    }
    int p, q;
    if (t < QH) { p = 0; q = t; }
    else { int u = t - QH; p = 1 + u / M2D; q = u % M2D; }
    int qq = (q < QH) ? q : (M2D - q);
    float sgn = (q < QH) ? 1.f : -1.f;
    float gr = 0.f, gi = 0.f;
    #pragma unroll
    for (int m1 = 0; m1 < M1D; m1++) {
        size_t o = ((size_t)(m1*QH + qq)*FD + f)*2;
        float ar = 0.f, ai = 0.f;
        #pragma unroll
        for (int ks = 0; ks < G1KS; ks++) {
            ar += G1p[(size_t)ks*G1SZ + o];
            ai += G1p[(size_t)ks*G1SZ + o + 1];
        }
        ai *= sgn;
        int pm = (p * m1) % M1D;
        float cr = wp[2*pm], ci = -wp[2*pm+1];
        gr += ar*cr - ai*ci;
        gi += ar*ci + ai*cr;
    }
    float scale = (t == 0) ? (1.0f/4545.0f) : (2.0f/4545.0f);
    unsigned int pk = (unsigned int)f2bf(gr*scale) | ((unsigned int)f2bf(-gi*scale) << 16);
    *(unsigned int*)&GmT[(size_t)f*KPAD + 2*t] = pk;
}

// one block (256 thr) per node: in-kernel float2 Z-pass + sparse clamped gather
__global__ __launch_bounds__(256) void attn_agg_kernel(const float* __restrict__ x,
                                                       const float* __restrict__ adj,
                                                       const float* __restrict__ xl,
                                                       const float* __restrict__ xr,
                                                       const float* __restrict__ sumx,
                                                       float* __restrict__ agg) {
    int node = blockIdx.x;
    int b = node >> 10;
    int tid = threadIdx.x;
    __shared__ float xr_s[CH], Zinv[CH], Sinv[CH];
    __shared__ float red16[16][CH];
    __shared__ int act_list[NN + 8];
    __shared__ int act_n;
    __shared__ float qv2[64][CH];

    if (tid < CH) xr_s[tid] = xr[(size_t)node*CH + tid];
    if (tid == 0) act_n = 0;
    __syncthreads();

    int c = tid & 31, jl = tid >> 5;
    const float* xlb = xl + ((size_t)b << 10) * CH;
    const float* adjrow = adj + (size_t)node * NN;

    int c2 = tid & 15, jl16 = tid >> 4;
    const float2* xlb2 = (const float2*)xlb;
    float xrcx = xr_s[2*c2], xrcy = xr_s[2*c2+1];
    float zx = 0.f, zy = 0.f;
    for (int j0 = jl16; j0 < NN; j0 += 128) {
        float2 sv[8];
        #pragma unroll
        for (int u = 0; u < 8; u++) sv[u] = xlb2[(size_t)(j0 + u*16)*16 + c2];
        #pragma unroll
        for (int u = 0; u < 8; u++) {
            float s0 = sv[u].x + xrcx; s0 = s0 > 0.f ? s0 : 0.01f * s0;
            float s1 = sv[u].y + xrcy; s1 = s1 > 0.f ? s1 : 0.01f * s1;
            zx += __expf(s0); zy += __expf(s1);
        }
    }
    red16[jl16][2*c2]   = zx;
    red16[jl16][2*c2+1] = zy;

    float av[4];
    #pragma unroll
    for (int u = 0; u < 4; u++) av[u] = adjrow[tid + u*256];
    __syncthreads();
    if (tid < CH) {
        float z = 0.f;
        #pragma unroll
        for (int r = 0; r < 16; r++) z += red16[r][tid];
        Zinv[tid] = FRCP(z);
    }
    #pragma unroll
    for (int u = 0; u < 4; u++)
        if (av[u] != 0.f) { int p = atomicAdd(&act_n, 1); act_list[p] = tid + u*256; }
    __syncthreads();
    int nact = act_n;

    int f = tid & 63, n0 = tid >> 6;
    int g = f >> 4;
    int c0 = n0*4 + g, c1 = (n0+4)*4 + g;
    const float* xb = x + ((size_t)b << 10) * FD;
    float acc0 = 0.f, acc1 = 0.f, sacc = 0.f;

    for (int base = 0; base < nact; base += 64) {
        int cnt = min(64, nact - base);
        int cntp = (cnt + 7) & ~7;
        for (int u = tid; u < (cnt << 5); u += 256) {
            int jj = u >> 5, cc = u & 31;
            int j = act_list[base + jj];
            float s = xlb[j*CH + cc] + xr_s[cc];
            s = s > 0.f ? s : 0.01f * s;
            float pv = __expf(s) * Zinv[cc];
            float qq = fmaxf(pv, 1e-6f) - 1e-6f;
            qv2[jj][cc] = qq;
            sacc += qq;
        }
        for (int u = tid + (cnt << 5); u < (cntp << 5); u += 256)
            qv2[u >> 5][u & 31] = 0.f;
        if (tid < cntp - cnt) act_list[base + cnt + tid] = act_list[base];
        __syncthreads();
        for (int jb = 0; jb < cntp; jb += 8) {
            float xv[8];
            #pragma unroll
            for (int u = 0; u < 8; u++) xv[u] = xb[act_list[base + jb + u]*FD + f];
            #pragma unroll
            for (int u = 0; u < 8; u++) {
                acc0 += qv2[jb+u][c0] * xv[u];
                acc1 += qv2[jb+u][c1] * xv[u];
            }
        }
        __syncthreads();
    }
    red16[jl][c] = sacc;
    __syncthreads();
    if (tid < CH) {
        float s = 0.f;
        #pragma unroll
        for (int r = 0; r < 8; r++) s += red16[r][tid];
        Sinv[tid] = FRCP(s + (float)NN * 1e-6f);
    }
    __syncthreads();
    float sx = sumx[b*FD + f] * 1e-6f;
    agg[(size_t)node*512 + n0*FD + f]       = (acc0 + sx) * Sinv[c0];
    agg[(size_t)node*512 + (n0+4)*FD + f]   = (acc1 + sx) * Sinv[c1];
}

// Fused A2-gemm + Y (round-14): block = (8-node slab, 64-col chunk).
// Phase 1: [64x64]@[64x64] tile gemm (agg slab @ Wt chunk) -> acc regs.
// Phase 2: acc -> LDS (reusing the A-tile buffer), each thread (node,qloc)
// computes its 9 half-grid Y values directly -- A2 never touches global.
// Grid stays 2048 blocks (round-11 lesson: never shrink below ~256 blocks).
__global__ __launch_bounds__(256) void ay_kernel(const float* __restrict__ agg,
                                                 const float* __restrict__ Wt,
                                                 unsigned short* __restrict__ Yb) {
    int slab = blockIdx.x, nt = blockIdx.y;
    int tid = threadIdx.x;
    __shared__ float As2[64][68];   // phase 1: A-tile [k][row]; phase 2: A2 chunk [row][2q+reim]
    __shared__ float Bs[64][64];    // Wt chunk [k][col]
    int tm = (tid >> 4) * 4, tf = (tid & 15) * 4;
    float ra[16], rb[16];
    #pragma unroll
    for (int i = 0; i < 16; i++) {
        int l = tid + i*256;
        int r = l >> 6, k = l & 63;
        ra[i] = agg[(size_t)(slab*64 + r)*64 + k];
    }
    #pragma unroll
    for (int i = 0; i < 16; i++) {
        int l = tid + i*256;
        int k = l >> 6, cc = l & 63;
        rb[i] = Wt[(size_t)k*512 + nt*64 + cc];
    }
    #pragma unroll
    for (int i = 0; i < 16; i++) { int l = tid + i*256; As2[l & 63][l >> 6] = ra[i]; }
    #pragma unroll
    for (int i = 0; i < 16; i++) { int l = tid + i*256; Bs[l >> 6][l & 63] = rb[i]; }
    __syncthreads();
    float acc[4][4] = {{0.f}};
    #pragma unroll 8
    for (int k = 0; k < 64; k++) {
        float4 a = *(const float4*)&As2[k][tm];
        float4 b = *(const float4*)&Bs[k][tf];
        acc[0][0] += a.x*b.x; acc[0][1] += a.x*b.y; acc[0][2] += a.x*b.z; acc[0][3] += a.x*b.w;
        acc[1][0] += a.y*b.x; acc[1][1] += a.y*b.y; acc[1][2] += a.y*b.z; acc[1][3] += a.y*b.w;
        acc[2][0] += a.z*b.x; acc[2][1] += a.z*b.y; acc[2][2] += a.z*b.z; acc[2][3] += a.z*b.w;
        acc[3][0] += a.w*b.x; acc[3][1] += a.w*b.y; acc[3][2] += a.w*b.z; acc[3][3] += a.w*b.w;
    }
    __syncthreads();   // all As2 reads complete before overwrite
    #pragma unroll
    for (int i = 0; i < 4; i++)
        #pragma unroll
        for (int j = 0; j < 4; j++)
            As2[tm + i][tf + j] = acc[i][j];
    __syncthreads();

    // phase 2: Y for q = nt*32 + qloc, node = slab*8 + (tid>>5)
    int qloc = tid & 31, node = tid >> 5;
    unsigned short* Yrow = Yb + (size_t)(slab*8 + node)*KPAD;
    int q = nt*32 + qloc;

    if (q <= 252) {
        float2 Av[8];
        #pragma unroll
        for (int n = 0; n < 8; n++)
            Av[n] = make_float2(As2[node*8 + n][2*qloc], As2[node*8 + n][2*qloc + 1]);

        const float CPt[5] = {1.0f, 0.766044443119f, 0.173648177667f, -0.5f, -0.939692620786f};
        const float SPt[5] = {0.0f, -0.642787609687f, -0.984807753012f, -0.866025403784f, -0.342020143326f};

        #define Y_PROD(CSIGN, TIDX)                                            \
        {                                                                      \
            float Pr = 1.f, Pi = 0.f, rp2 = 1.f;                               \
            _Pragma("unroll")                                                  \
            for (int n = 0; n < 8; n++) {                                      \
                float Xr = cp - Av[n].x, Xi = sp - (CSIGN) * Av[n].y;          \
                rp2 *= (Xr*Xr + Xi*Xi);                                        \
                float nPr = Pr*Xr - Pi*Xi;                                     \
                Pi = Pr*Xi + Pi*Xr; Pr = nPr;                                  \
            }                                                                  \
            float pAbs = FSQRT(Pr*Pr + Pi*Pi);                                 \
            float rp8 = FSQRT(FSQRT(FSQRT(FSQRT(rp2))));                       \
            float s = rp8 * FRCP(fmaxf(pAbs, 1e-20f));                         \
            unsigned int pk = (unsigned int)f2bf(s*Pr) | ((unsigned int)f2bf(s*Pi) << 16); \
            *(unsigned int*)&Yrow[2*(TIDX)] = pk;                              \
        }

        #pragma unroll
        for (int p = 0; p < 5; p++) {
            float cp = CPt[p], sp = SPt[p];
            int tfwd = (p == 0) ? q : (QH + (p-1)*M2D + q);
            Y_PROD(1.f, tfwd);
            if (p >= 1 && q >= 1) {
                int tmir = QH + (p-1)*M2D + (M2D - q);
                Y_PROD(-1.f, tmir);
            }
        }
        #undef Y_PROD
    }
    // zero the pad region [2*THALF, KPAD) for the slab's 8 rows (nt==7 blocks)
    if (nt == 7 && tid < 248) {
        int rr = tid / 31, cc2 = tid % 31;
        unsigned short* Yr2 = Yb + (size_t)(slab*8 + rr)*KPAD;
        *(unsigned int*)&Yr2[2*THALF + 2*cc2] = 0u;
    }
}

// MFMA bf16 gemm: part[kc] = Y[:, kc] @ GmatT^T ; grid (32 mtiles, 16 kc).
__global__ __launch_bounds__(256) void gemm_kernel(const unsigned short* __restrict__ Yb,
                                                   const unsigned short* __restrict__ GmT,
                                                   float* __restrict__ part) {
    int mtile = blockIdx.x, kc = blockIdx.y;
    int tid = threadIdx.x;
    __shared__ unsigned short Ys[64*40];   // [m][k], stride 40 bf16
    __shared__ unsigned short Gs[64*40];   // [n][k], stride 40
    int m0 = mtile * 64;
    int k0 = kc * KCHUNK;
    int r = tid >> 2, kg = (tid & 3) * 8;
    const unsigned short* Ysrc = Yb + (size_t)(m0 + r)*KPAD + k0 + kg;
    const unsigned short* Gsrc = GmT + (size_t)r*KPAD + k0 + kg;
    uint4 ya = *(const uint4*)Ysrc;
    uint4 ga = *(const uint4*)Gsrc;
    int w = tid >> 6, lane = tid & 63;
    int lm = lane & 15, quad = lane >> 4;
    f32x4 acc0 = {0.f,0.f,0.f,0.f}, acc1 = acc0, acc2 = acc0, acc3 = acc0;
    for (int ks = 0; ks < KCHUNK; ks += 32) {
        *(uint4*)&Ys[r*40 + kg] = ya;
        *(uint4*)&Gs[r*40 + kg] = ga;
        __syncthreads();
        if (ks + 32 < KCHUNK) {
            ya = *(const uint4*)(Ysrc + ks + 32);
            ga = *(const uint4*)(Gsrc + ks + 32);
        }
        short8 b  = *(const short8*)&Gs[(w*16 + lm)*40 + quad*8];
        short8 a0 = *(const short8*)&Ys[(lm)*40      + quad*8];
        short8 a1 = *(const short8*)&Ys[(16 + lm)*40 + quad*8];
        short8 a2 = *(const short8*)&Ys[(32 + lm)*40 + quad*8];
        short8 a3 = *(const short8*)&Ys[(48 + lm)*40 + quad*8];
        acc0 = __builtin_amdgcn_mfma_f32_16x16x32_bf16(a0, b, acc0, 0, 0, 0);
        acc1 = __builtin_amdgcn_mfma_f32_16x16x32_bf16(a1, b, acc1, 0, 0, 0);
        acc2 = __builtin_amdgcn_mfma_f32_16x16x32_bf16(a2, b, acc2, 0, 0, 0);
        acc3 = __builtin_amdgcn_mfma_f32_16x16x32_bf16(a3, b, acc3, 0, 0, 0);
        __syncthreads();
    }
    float* prow = part + (size_t)kc * (2048*FD);
    int col = w*16 + lm;
    #pragma unroll
    for (int rr = 0; rr < 4; rr++) {
        int row = quad*4 + rr;
        prow[(size_t)(m0 + row)*FD + col]      = acc0[rr];
        prow[(size_t)(m0 + 16 + row)*FD + col] = acc1[rr];
        prow[(size_t)(m0 + 32 + row)*FD + col] = acc2[rr];
        prow[(size_t)(m0 + 48 + row)*FD + col] = acc3[rr];
    }
}

// sum 16 partials + bias + mask -> out
__global__ __launch_bounds__(256) void reduce_kernel(const float* __restrict__ part,
                                                     const float* __restrict__ bm,
                                                     const float* __restrict__ mask,
                                                     float* __restrict__ out) {
    int idx = blockIdx.x * 256 + threadIdx.x;
    if (idx >= 32768) return;
    const float4* p4 = (const float4*)part;
    float4 s = p4[idx];
    #pragma unroll
    for (int kc = 1; kc < KSPLIT; kc++) {
        float4 v = p4[(size_t)kc*32768 + idx];
        s.x += v.x; s.y += v.y; s.z += v.z; s.w += v.w;
    }
    int f0 = (idx & 15) * 4;
    int node = idx >> 4;
    float mk = mask[node];
    s.x = (s.x + bm[f0])   * mk;
    s.y = (s.y + bm[f0+1]) * mk;
    s.z = (s.z + bm[f0+2]) * mk;
    s.w = (s.w + bm[f0+3]) * mk;
    ((float4*)out)[idx] = s;
}

extern "C" void kernel_launch(void* const* d_in, const int* in_sizes, int n_in,
                              void* d_out, int out_size, void* d_ws, size_t ws_size,
                              hipStream_t stream) {
    const float* x    = (const float*)d_in[0];
    const float* adj  = (const float*)d_in[1];
    const float* mask = (const float*)d_in[2];
    const float* Wl   = (const float*)d_in[3];
    const float* bl   = (const float*)d_in[4];
    const float* Wr   = (const float*)d_in[5];
    const float* br   = (const float*)d_in[6];
    const float* Wm   = (const float*)d_in[9];
    const float* bm   = (const float*)d_in[10];
    float* out = (float*)d_out;
    float* ws  = (float*)d_ws;

    float* wp   = ws + OFF_WP;
    float* sumx = ws + OFF_SUMX;
    unsigned short* GmT = (unsigned short*)(ws + OFF_GMT);
    float* xl   = ws + OFF_XL;
    float* xr   = ws + OFF_XR;
    float* agg  = ws + OFF_AGG;
    float* part = ws + OFF_PART;
    float* T    = ws + OFF_Y;     // alias: T dead before ay_kernel writes Yb
    unsigned short* Yb = (unsigned short*)(ws + OFF_Y);
    float* Wt   = ws + OFF_WT;
    float* G1p  = ws + OFF_G1P;

    hipLaunchKernelGGL(build_tw_kernel, dim3((506*512 + 64*512 + 255)/256), dim3(256), 0, stream, T, Wt, wp, sumx);
    hipLaunchKernelGGL(proj_kernel, dim3(2080), dim3(64), 0, stream, x, Wl, bl, Wr, br, xl, xr, sumx);
    hipLaunchKernelGGL(g1_gemm_kernel, dim3(8, 9, G1KS), dim3(256), 0, stream, T, Wm, G1p);
    hipLaunchKernelGGL(gmat_kernel, dim3(KPAD/2), dim3(64), 0, stream, G1p, wp, GmT);
    hipLaunchKernelGGL(attn_agg_kernel, dim3(2048), dim3(256), 0, stream, x, adj, xl, xr, sumx, agg);
    hipLaunchKernelGGL(ay_kernel, dim3(256, 8), dim3(256), 0, stream, agg, Wt, Yb);
    hipLaunchKernelGGL(gemm_kernel, dim3(32, KSPLIT), dim3(256), 0, stream, Yb, GmT, part);
    hipLaunchKernelGGL(reduce_kernel, dim3(128), dim3(256), 0, stream, part, bm, mask, out);
}